// Round 12
// baseline (154.993 us; speedup 1.0000x reference)
//
#include <hip/hip_runtime.h>
#include <hip/hip_bf16.h>
#include <cstdint>

#define B_   2
#define L_   2048
#define DIM_ 1024
#define H_   16
#define HD_  64
#define M_   (B_ * L_)    // 4096
#define N3_  (3 * DIM_)   // 3072
#define NSPL 2            // flash K-split factor

typedef unsigned short ushort_t;
typedef __bf16 bf16x8 __attribute__((ext_vector_type(8)));
typedef float  f32x4  __attribute__((ext_vector_type(4)));
typedef float  f32x16 __attribute__((ext_vector_type(16)));
typedef unsigned u32x2_t __attribute__((ext_vector_type(2)));

// native cast -> compiler emits v_cvt_pk_bf16_f32 for adjacent pairs (RTNE)
__device__ __forceinline__ unsigned short f2b(float f) {
  return __builtin_bit_cast(unsigned short, (__bf16)f);
}
__device__ __forceinline__ float b2f(unsigned short s) {
  unsigned u = ((unsigned)s) << 16;
  return __builtin_bit_cast(float, u);
}
__device__ __forceinline__ float fmax3(float a, float b, float c) {
  return fmaxf(fmaxf(a, b), c);   // fuses to v_max3_f32
}

// {a,b} -> a' = [a_lo | b_lo], b' = [a_hi | b_hi]  (lane halves)
__device__ __forceinline__ void plswap(unsigned &a, unsigned &b) {
#if defined(__has_builtin) && __has_builtin(__builtin_amdgcn_permlane32_swap)
  u32x2_t r = __builtin_amdgcn_permlane32_swap(a, b, false, false);
  a = r[0]; b = r[1];
#else
  unsigned sa = (unsigned)__shfl_xor((int)a, 32);
  unsigned sb = (unsigned)__shfl_xor((int)b, 32);
  bool hi = (threadIdx.x & 32) != 0;
  unsigned na = hi ? sb : a;
  unsigned nb = hi ? b : sa;
  a = na; b = nb;
#endif
}

typedef const __attribute__((address_space(1))) void* as1cp;
typedef __attribute__((address_space(3))) void* as3p;
__device__ __forceinline__ void gload_lds16(const void* g, void* l) {
  __builtin_amdgcn_global_load_lds((as1cp)g, (as3p)l, 16, 0, 0);
}

// XCD-aware bijective swizzle of a linear block id (requires nwg % 8 == 0):
// XCD j gets nwg/8 CONSECUTIVE work ids -> neighboring tiles share L2 panels.
__device__ __forceinline__ int xcd_swz(int bid, int nwg) {
  return (bid & 7) * (nwg >> 3) + (bid >> 3);
}

// ---------------- preprocessing (weights + rope only; x handled in gemm) ----------------
// blk [0,768):     Wqkv  f32 [1024][3072] -> bf16 [3072][1024] transpose
// blk [768,1024):  Wproj f32 [1024][1024] -> bf16 [1024][1024] transpose
// blk [1024,1280): rope cos/sin table [2048][32]
__global__ __launch_bounds__(256)
void preproc(const float* __restrict__ Wqkv, ushort_t* __restrict__ WqkvT,
             const float* __restrict__ Wproj, ushort_t* __restrict__ WprojT,
             float* __restrict__ cosT, float* __restrict__ sinT) {
  __shared__ float tile[64][65];
  const int blk = blockIdx.x;
  const int t = threadIdx.x;
  if (blk < 1024) {
    const float* in;
    ushort_t* out;
    int C, bi;
    if (blk < 768) { in = Wqkv; out = WqkvT; C = 3072; bi = blk; }
    else           { in = Wproj; out = WprojT; C = 1024; bi = blk - 768; }
    const int nbx = C >> 6;
    const int bx = bi % nbx, by = bi / nbx;
    const int r0 = by * 64, c0 = bx * 64;
    const int R = 1024;
#pragma unroll
    for (int p = 0; p < 4; ++p) {
      int r = (t >> 4) + p * 16;
      int c = (t & 15) * 4;
      float4 v = *(const float4*)&in[(size_t)(r0 + r) * C + (c0 + c)];
      tile[r][c + 0] = v.x; tile[r][c + 1] = v.y;
      tile[r][c + 2] = v.z; tile[r][c + 3] = v.w;
    }
    __syncthreads();
#pragma unroll
    for (int p = 0; p < 4; ++p) {
      int cc = (t >> 4) + p * 16;
      int r  = (t & 15) * 4;
      ushort4 o;
      o.x = f2b(tile[r + 0][cc]); o.y = f2b(tile[r + 1][cc]);
      o.z = f2b(tile[r + 2][cc]); o.w = f2b(tile[r + 3][cc]);
      *(ushort4*)&out[(size_t)(c0 + cc) * R + (r0 + r)] = o;
    }
  } else {
    int idx = (blk - 1024) * 256 + t;   // 65536 = 2048*32
    int l = idx >> 5, d = idx & 31;
    float inv_freq = expf(-((float)(2 * d) / 64.f) * logf(10000.f));
    float ang = (float)l * inv_freq;
    cosT[idx] = cosf(ang);
    sinT[idx] = sinf(ang);
  }
}

// ---------------- QKV GEMM: 128x128 tile, BK=32 (R7 structure) ----------------
// 4 waves (2x2), 16x16x32 MFMA, XCD-swizzled blocks.
// A is f32 x, converted to bf16 DURING staging (reg-stage + cvt_pk +
// ds_write_b128, same linear As layout as the gload path); B via gload_lds
// issued first so it flies under the conversion.  Epilogue: q,k cols
// [0,2048): fused per-head RMSNorm + RoPE (wave's 64-col slice = one head);
// Q prescaled by 0.125*log2(e).  V cols [2048,3072) -> vt[b][d][l].
__global__ __launch_bounds__(256)
void gemm_qkv(const float* __restrict__ Ax, const ushort_t* __restrict__ BT,
              ushort_t* __restrict__ Cqk, ushort_t* __restrict__ vtout,
              const float* __restrict__ qsc_, const float* __restrict__ ksc_,
              const float* __restrict__ cosT, const float* __restrict__ sinT) {
  const int K = DIM_;
  __shared__ ushort_t As[128 * 32];
  __shared__ ushort_t Bs[128 * 32];
  const int lane = threadIdx.x & 63;
  const int wid  = threadIdx.x >> 6;
  const int wm = wid >> 1, wn = wid & 1;
  // XCD swizzle: 768 blocks (768 % 8 == 0), XCD gets 96 consecutive tiles
  const int nwg = gridDim.x * gridDim.y;
  const int swz = xcd_swz(blockIdx.y * gridDim.x + blockIdx.x, nwg);
  const int m0 = (swz / gridDim.x) * 128, n0 = (swz % gridDim.x) * 128;
  const int ro = lane & 15, kg = lane >> 4;

  f32x4 acc[4][4] = {};

  for (int k0 = 0; k0 < K; k0 += 32) {
    const int cb = wid * 128;
    // B first: async gload_lds in flight during A conversion
#pragma unroll
    for (int j = 0; j < 2; ++j) {
      int c = cb + j * 64 + lane;
      gload_lds16(BT + (size_t)(n0 + (c >> 2)) * K + k0 + (c & 3) * 8,
                  &Bs[(cb + j * 64) * 8]);
    }
    // A: reg-stage f32 -> bf16 -> LDS (identical linear layout)
    float4 va[2][2];
#pragma unroll
    for (int j = 0; j < 2; ++j) {
      int c = cb + j * 64 + lane;
      const float* ap = Ax + (size_t)(m0 + (c >> 2)) * K + k0 + (c & 3) * 8;
      va[j][0] = *(const float4*)ap;
      va[j][1] = *(const float4*)(ap + 4);
    }
#pragma unroll
    for (int j = 0; j < 2; ++j) {
      int c = cb + j * 64 + lane;
      unsigned p0 = (unsigned)f2b(va[j][0].x) | ((unsigned)f2b(va[j][0].y) << 16);
      unsigned p1 = (unsigned)f2b(va[j][0].z) | ((unsigned)f2b(va[j][0].w) << 16);
      unsigned p2 = (unsigned)f2b(va[j][1].x) | ((unsigned)f2b(va[j][1].y) << 16);
      unsigned p3 = (unsigned)f2b(va[j][1].z) | ((unsigned)f2b(va[j][1].w) << 16);
      uint4 w; w.x = p0; w.y = p1; w.z = p2; w.w = p3;
      *(uint4*)&As[c * 8] = w;                 // ds_write_b128
    }
    __syncthreads();
    bf16x8 af[4], bfr[4];
#pragma unroll
    for (int i = 0; i < 4; ++i)
      af[i] = *(const bf16x8*)&As[(wm * 64 + i * 16 + ro) * 32 + kg * 8];
#pragma unroll
    for (int i = 0; i < 4; ++i)
      bfr[i] = *(const bf16x8*)&Bs[(wn * 64 + i * 16 + ro) * 32 + kg * 8];
#pragma unroll
    for (int i = 0; i < 4; ++i)
#pragma unroll
      for (int j = 0; j < 4; ++j)
        acc[i][j] = __builtin_amdgcn_mfma_f32_16x16x32_bf16(af[i], bfr[j],
                                                            acc[i][j], 0, 0, 0);
    __syncthreads();
  }

  if (n0 < 2048) {
    // fused RMSNorm + RoPE.  d = j*16 + ro within this wave's head.
    const int ic = (n0 >= 1024);             // 0 = q, 1 = k (block-uniform)
    const float* scp = ic ? ksc_ : qsc_;
    const float qsc = ic ? 1.f : 0.125f * 1.44269504088896341f;
    float sc[4];
#pragma unroll
    for (int j = 0; j < 4; ++j) sc[j] = scp[j * 16 + ro];
#pragma unroll
    for (int i = 0; i < 4; ++i)
#pragma unroll
      for (int r = 0; r < 4; ++r) {
        int row = m0 + wm * 64 + i * 16 + kg * 4 + r;
        int l = row & (L_ - 1);
        float x0 = acc[i][0][r], x1 = acc[i][1][r];
        float x2 = acc[i][2][r], x3 = acc[i][3][r];
        float ss = x0 * x0 + x1 * x1 + x2 * x2 + x3 * x3;
        ss += __shfl_xor(ss, 1); ss += __shfl_xor(ss, 2);
        ss += __shfl_xor(ss, 4); ss += __shfl_xor(ss, 8);
        float inv = rsqrtf(ss * (1.f / 64.f) + 1e-6f);
        x0 *= inv * sc[0]; x1 *= inv * sc[1];
        x2 *= inv * sc[2]; x3 *= inv * sc[3];
        float cv0 = cosT[l * 32 + ro],      sv0 = sinT[l * 32 + ro];
        float cv1 = cosT[l * 32 + 16 + ro], sv1 = sinT[l * 32 + 16 + ro];
        float o0 = (x0 * cv0 - x2 * sv0) * qsc;
        float o1 = (x1 * cv1 - x3 * sv1) * qsc;
        float o2 = (x2 * cv0 + x0 * sv0) * qsc;
        float o3 = (x3 * cv1 + x1 * sv1) * qsc;
        ushort_t* cp = Cqk + (size_t)row * 2048 + n0 + wn * 64 + ro;
        cp[0]  = f2b(o0);
        cp[16] = f2b(o1);
        cp[32] = f2b(o2);
        cp[48] = f2b(o3);
      }
  } else {
    // V columns -> vt[b][dg][l], 4 consecutive l per lane packed
#pragma unroll
    for (int i = 0; i < 4; ++i) {
      int rowb = m0 + wm * 64 + i * 16 + kg * 4;
      int bb = rowb >> 11, l = rowb & (L_ - 1);
#pragma unroll
      for (int j = 0; j < 4; ++j) {
        int dg = (n0 - 2048) + wn * 64 + j * 16 + ro;
        ushort4 o;
        o.x = f2b(acc[i][j][0]); o.y = f2b(acc[i][j][1]);
        o.z = f2b(acc[i][j][2]); o.w = f2b(acc[i][j][3]);
        *(ushort4*)&vtout[((size_t)bb * DIM_ + dg) * L_ + l] = o;
      }
    }
  }
}

// ---------------- proj GEMM: plain (R7 structure), f32 out + bias ----------------
// 128x128 tile, BK=32, 4 waves, 16x16x32 MFMA, gload_lds, XCD-swizzled blocks.
__global__ __launch_bounds__(256)
void gemm_proj(const ushort_t* __restrict__ A, const ushort_t* __restrict__ BT,
               float* __restrict__ Cout, const float* __restrict__ bias) {
  const int K = DIM_;
  __shared__ ushort_t As[128 * 32];
  __shared__ ushort_t Bs[128 * 32];
  const int lane = threadIdx.x & 63;
  const int wid  = threadIdx.x >> 6;
  const int wm = wid >> 1, wn = wid & 1;
  // XCD swizzle: 256 blocks (256 % 8 == 0)
  const int nwg = gridDim.x * gridDim.y;
  const int swz = xcd_swz(blockIdx.y * gridDim.x + blockIdx.x, nwg);
  const int m0 = (swz / gridDim.x) * 128, n0 = (swz % gridDim.x) * 128;
  const int ro = lane & 15, kg = lane >> 4;

  f32x4 acc[4][4] = {};

  for (int k0 = 0; k0 < K; k0 += 32) {
    const int cb = wid * 128;
#pragma unroll
    for (int j = 0; j < 2; ++j) {
      int c = cb + j * 64 + lane;
      gload_lds16(A + (size_t)(m0 + (c >> 2)) * K + k0 + (c & 3) * 8,
                  &As[(cb + j * 64) * 8]);
    }
#pragma unroll
    for (int j = 0; j < 2; ++j) {
      int c = cb + j * 64 + lane;
      gload_lds16(BT + (size_t)(n0 + (c >> 2)) * K + k0 + (c & 3) * 8,
                  &Bs[(cb + j * 64) * 8]);
    }
    __syncthreads();
    bf16x8 af[4], bfr[4];
#pragma unroll
    for (int i = 0; i < 4; ++i)
      af[i] = *(const bf16x8*)&As[(wm * 64 + i * 16 + ro) * 32 + kg * 8];
#pragma unroll
    for (int i = 0; i < 4; ++i)
      bfr[i] = *(const bf16x8*)&Bs[(wn * 64 + i * 16 + ro) * 32 + kg * 8];
#pragma unroll
    for (int i = 0; i < 4; ++i)
#pragma unroll
      for (int j = 0; j < 4; ++j)
        acc[i][j] = __builtin_amdgcn_mfma_f32_16x16x32_bf16(af[i], bfr[j],
                                                            acc[i][j], 0, 0, 0);
    __syncthreads();
  }

#pragma unroll
  for (int i = 0; i < 4; ++i)
#pragma unroll
    for (int r = 0; r < 4; ++r) {
      int row = m0 + wm * 64 + i * 16 + kg * 4 + r;
#pragma unroll
      for (int j = 0; j < 4; ++j) {
        int col = n0 + wn * 64 + j * 16 + ro;
        Cout[(size_t)row * DIM_ + col] = acc[i][j][r] + bias[col];
      }
    }
}

// ---------------- flash attention, 32x32 MFMA, joint half-tiles, K-split x2 ----------------
// SPLIT=1: grid (L/128, H, B*NSPL), half K range per block (16 tiles),
// bf16 partials + (m,l).  SPLIT=0: single pass -> bf16 O.
template <int SPLIT>
__global__ __launch_bounds__(256, 3)
void flash_attn(const ushort_t* __restrict__ qk, const ushort_t* __restrict__ vt,
                ushort_t* __restrict__ O, ushort_t* __restrict__ Opart,
                float* __restrict__ Ml) {
  const int qt = blockIdx.x, h = blockIdx.y;
  const int b  = SPLIT ? (int)(blockIdx.z >> 1) : (int)blockIdx.z;
  const int ks = SPLIT ? (int)(blockIdx.z & 1) : 0;
  const int ktBeg = SPLIT ? ks * (L_ / 64 / NSPL) : 0;   // 16 tiles per split
  const int ktEnd = SPLIT ? ktBeg + (L_ / 64 / NSPL) : (L_ / 64);
  const int lane = threadIdx.x & 63, wid = threadIdx.x >> 6;
  const int lq = lane & 31;          // q (QK) / d' (PV A) / col index
  const int hi = lane >> 5;          // lane-half: k-slice half selector
  const int q0 = qt * 128;
  const size_t tok0 = (size_t)b * L_;
  const ushort_t* qb = qk + tok0 * 2048 + h * HD_;
  const ushort_t* kb = qb + DIM_;
  const ushort_t* vb = vt + ((size_t)b * DIM_ + h * HD_) * L_;

  __shared__ ushort_t Ks[2][4096];   // [kpos 64][d 64], 16B-chunk XOR swizzle
  __shared__ ushort_t Vs[2][4096];   // [d 64][kpos 64], same swizzle

  const int srow0 = wid * 16 + (lane >> 3);
  const int sc    = (lane & 7) ^ (srow0 & 7);
  const ushort_t* kst = kb + (size_t)(ktBeg * 64 + srow0) * 2048 + sc * 8;
  const ushort_t* vst = vb + (size_t)srow0 * L_ + ktBeg * 64 + sc * 8;
  auto STAGE = [&](int bufi) {
    gload_lds16(kst,            &Ks[bufi][wid * 1024]);
    gload_lds16(kst + 8 * 2048, &Ks[bufi][wid * 1024 + 512]);
    gload_lds16(vst,            &Vs[bufi][wid * 1024]);
    gload_lds16(vst + 8 * L_,   &Vs[bufi][wid * 1024 + 512]);
    kst += 64 * 2048;
    vst += 64;
  };

  // Q fragments: B-operand of QK^T.  qf[s]: Q[q=lq][d = 16s + hi*8 + j]
  bf16x8 qf[4];
  {
    const ushort_t* gp = qb + (size_t)(q0 + wid * 32 + lq) * 2048;
#pragma unroll
    for (int s = 0; s < 4; ++s)
      qf[s] = *(const bf16x8*)(gp + s * 16 + hi * 8);
  }

  // ones A-operand: row-sum of P on the matrix pipe
  bf16x8 onesv;
#pragma unroll
  for (int i = 0; i < 8; ++i) onesv[i] = (__bf16)1.0f;

  int chs[4];
#pragma unroll
  for (int s = 0; s < 4; ++s) chs[s] = ((2 * s + hi) ^ (lq & 7)) * 8;

  f32x16 oaccT[2] = {};              // [dtile] D[row=d'][col=q=lq]
  f32x16 laccv = {};                 // ones-MFMA row-sum; only [0] consumed
  float mrow = 0.f;                  // absolute running max (shifted trigger)

  STAGE(0);
  __syncthreads();

  auto TILE = [&](int bi, bool more) {
    if (more) STAGE(bi ^ 1);
    const ushort_t* kb0 = &Ks[bi][lq * 64];
    const ushort_t* vb0 = &Vs[bi][lq * 64];

    // QK both half-tiles, C-init = -mrow: st = S - mrow (shifted domain)
    f32x16 st0, st1;
#pragma unroll
    for (int i = 0; i < 16; ++i) { st0[i] = -mrow; st1[i] = -mrow; }
    __builtin_amdgcn_s_setprio(1);
#pragma unroll
    for (int s = 0; s < 4; ++s) {
      bf16x8 kf0 = *(const bf16x8*)(kb0 + chs[s]);
      bf16x8 kf1 = *(const bf16x8*)(kb0 + 2048 + chs[s]);
      st0 = __builtin_amdgcn_mfma_f32_32x32x16_bf16(kf0, qf[s], st0, 0, 0, 0);
      st1 = __builtin_amdgcn_mfma_f32_32x32x16_bf16(kf1, qf[s], st1, 0, 0, 0);
    }
    __builtin_amdgcn_s_setprio(0);

    // joint shifted max over 32 values (max3 tree) + cross-half
    float a0 = fmax3(st0[0],  st0[1],  st0[2]);
    float a1 = fmax3(st0[3],  st0[4],  st0[5]);
    float a2 = fmax3(st0[6],  st0[7],  st0[8]);
    float a3 = fmax3(st0[9],  st0[10], st0[11]);
    float a4 = fmax3(st0[12], st0[13], st0[14]);
    float a5 = fmax3(st0[15], st1[0],  st1[1]);
    float a6 = fmax3(st1[2],  st1[3],  st1[4]);
    float a7 = fmax3(st1[5],  st1[6],  st1[7]);
    float a8 = fmax3(st1[8],  st1[9],  st1[10]);
    float a9 = fmax3(st1[11], st1[12], st1[13]);
    float aa = fmaxf(st1[14], st1[15]);
    float c0 = fmax3(a0, a1, a2);
    float c1 = fmax3(a3, a4, a5);
    float c2 = fmax3(a6, a7, a8);
    float c3 = fmax3(a9, aa, c0);
    float pm = fmax3(c1, c2, c3);
    pm = fmaxf(pm, __shfl_xor(pm, 32));

    // defer-max: rescale only when max grew by >8 over mrow (log2 domain)
    if (__any(pm > 8.f)) {
      float d = fmaxf(pm, 0.f);
      float alpha = __builtin_amdgcn_exp2f(-d);
      mrow += d;
      laccv[0] *= alpha;
#pragma unroll
      for (int dt = 0; dt < 2; ++dt)
#pragma unroll
        for (int r = 0; r < 16; ++r) oaccT[dt][r] *= alpha;
#pragma unroll
      for (int i = 0; i < 16; ++i) { st0[i] -= d; st1[i] -= d; }
    }

    // P = exp2(st), packed bf16 pairs
    unsigned pk0[8], pk1[8];
#pragma unroll
    for (int p = 0; p < 8; ++p) {
      float e0 = __builtin_amdgcn_exp2f(st0[2 * p]);
      float e1 = __builtin_amdgcn_exp2f(st0[2 * p + 1]);
      pk0[p] = (unsigned)f2b(e0) | ((unsigned)f2b(e1) << 16);
      float f0 = __builtin_amdgcn_exp2f(st1[2 * p]);
      float f1 = __builtin_amdgcn_exp2f(st1[2 * p + 1]);
      pk1[p] = (unsigned)f2b(f0) | ((unsigned)f2b(f1) << 16);
    }

    // PV: redistribute P via permlane32_swap into B-fragments
    __builtin_amdgcn_s_setprio(1);
#pragma unroll
    for (int t = 0; t < 2; ++t)
#pragma unroll
      for (int blk = 0; blk < 2; ++blk) {
        unsigned w0 = (t == 0) ? pk0[4 * blk + 0] : pk1[4 * blk + 0];
        unsigned w1 = (t == 0) ? pk0[4 * blk + 1] : pk1[4 * blk + 1];
        unsigned w2 = (t == 0) ? pk0[4 * blk + 2] : pk1[4 * blk + 2];
        unsigned w3 = (t == 0) ? pk0[4 * blk + 3] : pk1[4 * blk + 3];
        plswap(w0, w2);   // -> {j0j1, j4j5}
        plswap(w1, w3);   // -> {j2j3, j6j7}
        uint4 bw; bw.x = w0; bw.y = w1; bw.z = w2; bw.w = w3;
        bf16x8 pf = __builtin_bit_cast(bf16x8, bw);
        const int sg = 2 * t + blk;
        laccv = __builtin_amdgcn_mfma_f32_32x32x16_bf16(onesv, pf, laccv, 0, 0, 0);
#pragma unroll
        for (int dt = 0; dt < 2; ++dt) {
          bf16x8 vf = *(const bf16x8*)(vb0 + dt * 2048 + chs[sg]);
          oaccT[dt] = __builtin_amdgcn_mfma_f32_32x32x16_bf16(vf, pf,
                                                              oaccT[dt], 0, 0, 0);
        }
      }
    __builtin_amdgcn_s_setprio(0);

    __syncthreads();   // drains vmcnt: stage(next) complete; buffers safe
  };

  const int NT = ktEnd - ktBeg;      // 16 (split) or 32 (single), even
  for (int it = 0; it < NT; it += 2) {
    TILE(0, it + 1 < NT);
    TILE(1, it + 2 < NT);
  }

  const float lrow = laccv[0];
  const float linv = 1.f / lrow;
  const int tok = (int)tok0 + q0 + wid * 32 + lq;
  ushort_t* obp = (SPLIT ? Opart + (size_t)ks * M_ * DIM_ : O)
                  + (size_t)tok * DIM_ + h * HD_;
#pragma unroll
  for (int dt = 0; dt < 2; ++dt)
#pragma unroll
    for (int g4 = 0; g4 < 4; ++g4) {
      int d0 = dt * 32 + g4 * 8 + hi * 4;
      ushort4 o4;
      o4.x = f2b(oaccT[dt][4 * g4 + 0] * linv);
      o4.y = f2b(oaccT[dt][4 * g4 + 1] * linv);
      o4.z = f2b(oaccT[dt][4 * g4 + 2] * linv);
      o4.w = f2b(oaccT[dt][4 * g4 + 3] * linv);
      *(ushort4*)(obp + d0) = o4;
    }
  if (SPLIT && hi == 0) {
    float2 ml; ml.x = mrow; ml.y = lrow;
    *(float2*)&Ml[(((size_t)ks * M_ + tok) * H_ + h) * 2] = ml;
  }
}

// ---------------- combine NSPL K-split partials (bf16) -> bf16 O ----------------
// O = sum_i w_i*O_i, w_i = l_i*2^(m_i-M) / sum  (partials are normalized)
__global__ __launch_bounds__(256)
void attn_combine(const ushort_t* __restrict__ Opart, const float* __restrict__ Ml,
                  ushort_t* __restrict__ O) {
  int idx = blockIdx.x * 256 + threadIdx.x;   // 524288 threads, 8 bf16 each
  int c   = idx & 127;                        // chunk-of-8 within row
  int tok = idx >> 7;
  int h   = c >> 3;
  float2 ml[NSPL];
  float mM = -1e30f;
#pragma unroll
  for (int s = 0; s < NSPL; ++s) {
    ml[s] = *(const float2*)&Ml[(((size_t)s * M_ + tok) * H_ + h) * 2];
    mM = fmaxf(mM, ml[s].x);
  }
  float w[NSPL], sum = 0.f;
#pragma unroll
  for (int s = 0; s < NSPL; ++s) {
    w[s] = ml[s].y * __builtin_amdgcn_exp2f(ml[s].x - mM);
    sum += w[s];
  }
  float inv = 1.f / sum;
  size_t off = (size_t)tok * DIM_ + c * 8;
  float o[8] = {};
#pragma unroll
  for (int s = 0; s < NSPL; ++s) {
    uint4 a = *(const uint4*)&Opart[(size_t)s * M_ * DIM_ + off];
    float ws = w[s] * inv;
    const unsigned* pa = (const unsigned*)&a;
#pragma unroll
    for (int wd = 0; wd < 4; ++wd) {
      o[2 * wd]     += b2f((unsigned short)(pa[wd] & 0xffff)) * ws;
      o[2 * wd + 1] += b2f((unsigned short)(pa[wd] >> 16)) * ws;
    }
  }
  unsigned ow[4];
#pragma unroll
  for (int wd = 0; wd < 4; ++wd)
    ow[wd] = (unsigned)f2b(o[2 * wd]) | ((unsigned)f2b(o[2 * wd + 1]) << 16);
  uint4 ov; ov.x = ow[0]; ov.y = ow[1]; ov.z = ow[2]; ov.w = ow[3];
  *(uint4*)&O[off] = ov;
}

// ---------------- launch ----------------
extern "C" void kernel_launch(void* const* d_in, const int* in_sizes, int n_in,
                              void* d_out, int out_size, void* d_ws, size_t ws_size,
                              hipStream_t stream) {
  const float* x     = (const float*)d_in[0];
  const float* Wqkv  = (const float*)d_in[1];
  const float* qs    = (const float*)d_in[2];
  const float* ks    = (const float*)d_in[3];
  const float* Wproj = (const float*)d_in[4];
  const float* bproj = (const float*)d_in[5];
  float* out = (float*)d_out;

  char* ws = (char*)d_ws;
  ushort_t* WqkvT  = (ushort_t*)(ws + (size_t)(8u << 20));             // 6 MB
  ushort_t* WprojT = (ushort_t*)(ws + (size_t)(14u << 20));            // 2 MB
  ushort_t* qkb    = (ushort_t*)(ws + (size_t)(16u << 20));            // 16 MB [4096][2048]
  ushort_t* vtb    = (ushort_t*)(ws + (size_t)(32u << 20));            // 8 MB  [2][1024][2048]
  float*    cosT   = (float*)(ws + (size_t)(40u << 20));               // 256 KB
  float*    sinT   = (float*)(ws + (size_t)(40u << 20) + (256u << 10));// 256 KB
  ushort_t* ob     = (ushort_t*)(ws + (size_t)(41u << 20));            // 8 MB
  ushort_t* Opart  = (ushort_t*)(ws + (size_t)(49u << 20));            // 16 MB [2][4096][1024] bf16
  float*    Ml     = (float*)(ws + (size_t)(65u << 20));               // 1 MB  [2][4096][16][2] f32

  preproc<<<1280, 256, 0, stream>>>(Wqkv, WqkvT, Wproj, WprojT, cosT, sinT);
  gemm_qkv<<<dim3(24, 32), 256, 0, stream>>>(x, WqkvT, qkb, vtb,
                                             qs, ks, cosT, sinT);
  if (ws_size >= ((size_t)66u << 20)) {
    flash_attn<1><<<dim3(16, 16, B_ * NSPL), 256, 0, stream>>>(qkb, vtb, nullptr,
                                                               Opart, Ml);
    attn_combine<<<2048, 256, 0, stream>>>(Opart, Ml, ob);
  } else {
    flash_attn<0><<<dim3(16, 16, 2), 256, 0, stream>>>(qkb, vtb, ob,
                                                       nullptr, nullptr);
  }
  gemm_proj<<<dim3(8, 32), 256, 0, stream>>>(ob, WprojT, out, bproj);
}

// Round 13
// 140.642 us; speedup vs baseline: 1.1020x; 1.1020x over previous
//
#include <hip/hip_runtime.h>
#include <hip/hip_bf16.h>
#include <cstdint>

#define B_   2
#define L_   2048
#define DIM_ 1024
#define H_   16
#define HD_  64
#define M_   (B_ * L_)    // 4096
#define N3_  (3 * DIM_)   // 3072
#define NSPL 2            // flash K-split factor

typedef unsigned short ushort_t;
typedef __bf16 bf16x8 __attribute__((ext_vector_type(8)));
typedef float  f32x4  __attribute__((ext_vector_type(4)));
typedef float  f32x16 __attribute__((ext_vector_type(16)));
typedef unsigned u32x2_t __attribute__((ext_vector_type(2)));

// native cast -> compiler emits v_cvt_pk_bf16_f32 for adjacent pairs (RTNE)
__device__ __forceinline__ unsigned short f2b(float f) {
  return __builtin_bit_cast(unsigned short, (__bf16)f);
}
__device__ __forceinline__ float b2f(unsigned short s) {
  unsigned u = ((unsigned)s) << 16;
  return __builtin_bit_cast(float, u);
}
__device__ __forceinline__ float fmax3(float a, float b, float c) {
  return fmaxf(fmaxf(a, b), c);   // fuses to v_max3_f32
}

// {a,b} -> a' = [a_lo | b_lo], b' = [a_hi | b_hi]  (lane halves)
__device__ __forceinline__ void plswap(unsigned &a, unsigned &b) {
#if defined(__has_builtin) && __has_builtin(__builtin_amdgcn_permlane32_swap)
  u32x2_t r = __builtin_amdgcn_permlane32_swap(a, b, false, false);
  a = r[0]; b = r[1];
#else
  unsigned sa = (unsigned)__shfl_xor((int)a, 32);
  unsigned sb = (unsigned)__shfl_xor((int)b, 32);
  bool hi = (threadIdx.x & 32) != 0;
  unsigned na = hi ? sb : a;
  unsigned nb = hi ? b : sa;
  a = na; b = nb;
#endif
}

typedef const __attribute__((address_space(1))) void* as1cp;
typedef __attribute__((address_space(3))) void* as3p;
__device__ __forceinline__ void gload_lds16(const void* g, void* l) {
  __builtin_amdgcn_global_load_lds((as1cp)g, (as3p)l, 16, 0, 0);
}

// XCD-aware bijective swizzle of a linear block id (requires nwg % 8 == 0):
// XCD j gets nwg/8 CONSECUTIVE work ids -> neighboring tiles share L2 panels.
__device__ __forceinline__ int xcd_swz(int bid, int nwg) {
  return (bid & 7) * (nwg >> 3) + (bid >> 3);
}

// ---------------- fused preprocessing ----------------
// blk [0,4096):      f32 -> bf16 convert of x (1M float4)
// blk [4096,4864):   Wqkv  f32 [1024][3072] -> bf16 [3072][1024] transpose
// blk [4864,5120):   Wproj f32 [1024][1024] -> bf16 [1024][1024] transpose
// blk [5120,5376):   rope cos/sin table [2048][32]
__global__ __launch_bounds__(256)
void preproc(const float* __restrict__ x, ushort_t* __restrict__ xb,
             const float* __restrict__ Wqkv, ushort_t* __restrict__ WqkvT,
             const float* __restrict__ Wproj, ushort_t* __restrict__ WprojT,
             float* __restrict__ cosT, float* __restrict__ sinT) {
  __shared__ float tile[64][65];
  const int blk = blockIdx.x;
  const int t = threadIdx.x;
  if (blk < 4096) {
    int i = blk * 256 + t;
    float4 v = *(const float4*)&x[(size_t)i * 4];
    ushort4 o;
    o.x = f2b(v.x); o.y = f2b(v.y); o.z = f2b(v.z); o.w = f2b(v.w);
    *(ushort4*)&xb[(size_t)i * 4] = o;
  } else if (blk < 5120) {
    const float* in;
    ushort_t* out;
    int C, bi;
    if (blk < 4864) { in = Wqkv; out = WqkvT; C = 3072; bi = blk - 4096; }
    else            { in = Wproj; out = WprojT; C = 1024; bi = blk - 4864; }
    const int nbx = C >> 6;
    const int bx = bi % nbx, by = bi / nbx;
    const int r0 = by * 64, c0 = bx * 64;
    const int R = 1024;
#pragma unroll
    for (int p = 0; p < 4; ++p) {
      int r = (t >> 4) + p * 16;
      int c = (t & 15) * 4;
      float4 v = *(const float4*)&in[(size_t)(r0 + r) * C + (c0 + c)];
      tile[r][c + 0] = v.x; tile[r][c + 1] = v.y;
      tile[r][c + 2] = v.z; tile[r][c + 3] = v.w;
    }
    __syncthreads();
#pragma unroll
    for (int p = 0; p < 4; ++p) {
      int cc = (t >> 4) + p * 16;
      int r  = (t & 15) * 4;
      ushort4 o;
      o.x = f2b(tile[r + 0][cc]); o.y = f2b(tile[r + 1][cc]);
      o.z = f2b(tile[r + 2][cc]); o.w = f2b(tile[r + 3][cc]);
      *(ushort4*)&out[(size_t)(c0 + cc) * R + (r0 + r)] = o;
    }
  } else {
    int idx = (blk - 5120) * 256 + t;   // 65536 = 2048*32
    int l = idx >> 5, d = idx & 31;
    float inv_freq = expf(-((float)(2 * d) / 64.f) * logf(10000.f));
    float ang = (float)l * inv_freq;
    cosT[idx] = cosf(ang);
    sinT[idx] = sinf(ang);
  }
}

// ---------------- QKV GEMM: 128x128 tile, BK=32 (proven R7 structure) ----------------
// 4 waves (2x2), 16x16x32 MFMA, global_load_lds staging, XCD-swizzled blocks.
// q,k cols [0,2048): fused per-head RMSNorm + RoPE in the epilogue (wave's
// 64-col slice = exactly one head; q/k split at col 1024 block-uniform);
// Q prescaled by 0.125*log2(e).  V cols [2048,3072) -> vt[b][d][l].
__global__ __launch_bounds__(256)
void gemm_qkv(const ushort_t* __restrict__ A, const ushort_t* __restrict__ BT,
              ushort_t* __restrict__ Cqk, ushort_t* __restrict__ vtout,
              const float* __restrict__ qsc_, const float* __restrict__ ksc_,
              const float* __restrict__ cosT, const float* __restrict__ sinT) {
  const int K = DIM_;
  __shared__ ushort_t As[128 * 32];
  __shared__ ushort_t Bs[128 * 32];
  const int lane = threadIdx.x & 63;
  const int wid  = threadIdx.x >> 6;
  const int wm = wid >> 1, wn = wid & 1;
  // XCD swizzle: 768 blocks (768 % 8 == 0), XCD gets 96 consecutive tiles
  const int nwg = gridDim.x * gridDim.y;
  const int swz = xcd_swz(blockIdx.y * gridDim.x + blockIdx.x, nwg);
  const int m0 = (swz / gridDim.x) * 128, n0 = (swz % gridDim.x) * 128;
  const int ro = lane & 15, kg = lane >> 4;

  f32x4 acc[4][4] = {};

  for (int k0 = 0; k0 < K; k0 += 32) {
    const int cb = wid * 128;
#pragma unroll
    for (int j = 0; j < 2; ++j) {
      int c = cb + j * 64 + lane;
      gload_lds16(A + (size_t)(m0 + (c >> 2)) * K + k0 + (c & 3) * 8,
                  &As[(cb + j * 64) * 8]);
    }
#pragma unroll
    for (int j = 0; j < 2; ++j) {
      int c = cb + j * 64 + lane;
      gload_lds16(BT + (size_t)(n0 + (c >> 2)) * K + k0 + (c & 3) * 8,
                  &Bs[(cb + j * 64) * 8]);
    }
    __syncthreads();
    bf16x8 af[4], bfr[4];
#pragma unroll
    for (int i = 0; i < 4; ++i)
      af[i] = *(const bf16x8*)&As[(wm * 64 + i * 16 + ro) * 32 + kg * 8];
#pragma unroll
    for (int i = 0; i < 4; ++i)
      bfr[i] = *(const bf16x8*)&Bs[(wn * 64 + i * 16 + ro) * 32 + kg * 8];
#pragma unroll
    for (int i = 0; i < 4; ++i)
#pragma unroll
      for (int j = 0; j < 4; ++j)
        acc[i][j] = __builtin_amdgcn_mfma_f32_16x16x32_bf16(af[i], bfr[j],
                                                            acc[i][j], 0, 0, 0);
    __syncthreads();
  }

  if (n0 < 2048) {
    // fused RMSNorm + RoPE.  d = j*16 + ro within this wave's head.
    const int ic = (n0 >= 1024);             // 0 = q, 1 = k (block-uniform)
    const float* scp = ic ? ksc_ : qsc_;
    const float qsc = ic ? 1.f : 0.125f * 1.44269504088896341f;
    float sc[4];
#pragma unroll
    for (int j = 0; j < 4; ++j) sc[j] = scp[j * 16 + ro];
#pragma unroll
    for (int i = 0; i < 4; ++i)
#pragma unroll
      for (int r = 0; r < 4; ++r) {
        int row = m0 + wm * 64 + i * 16 + kg * 4 + r;
        int l = row & (L_ - 1);
        float x0 = acc[i][0][r], x1 = acc[i][1][r];
        float x2 = acc[i][2][r], x3 = acc[i][3][r];
        float ss = x0 * x0 + x1 * x1 + x2 * x2 + x3 * x3;
        ss += __shfl_xor(ss, 1); ss += __shfl_xor(ss, 2);
        ss += __shfl_xor(ss, 4); ss += __shfl_xor(ss, 8);
        float inv = rsqrtf(ss * (1.f / 64.f) + 1e-6f);
        x0 *= inv * sc[0]; x1 *= inv * sc[1];
        x2 *= inv * sc[2]; x3 *= inv * sc[3];
        float cv0 = cosT[l * 32 + ro],      sv0 = sinT[l * 32 + ro];
        float cv1 = cosT[l * 32 + 16 + ro], sv1 = sinT[l * 32 + 16 + ro];
        float o0 = (x0 * cv0 - x2 * sv0) * qsc;
        float o1 = (x1 * cv1 - x3 * sv1) * qsc;
        float o2 = (x2 * cv0 + x0 * sv0) * qsc;
        float o3 = (x3 * cv1 + x1 * sv1) * qsc;
        ushort_t* cp = Cqk + (size_t)row * 2048 + n0 + wn * 64 + ro;
        cp[0]  = f2b(o0);
        cp[16] = f2b(o1);
        cp[32] = f2b(o2);
        cp[48] = f2b(o3);
      }
  } else {
    // V columns -> vt[b][dg][l], 4 consecutive l per lane packed
#pragma unroll
    for (int i = 0; i < 4; ++i) {
      int rowb = m0 + wm * 64 + i * 16 + kg * 4;
      int bb = rowb >> 11, l = rowb & (L_ - 1);
#pragma unroll
      for (int j = 0; j < 4; ++j) {
        int dg = (n0 - 2048) + wn * 64 + j * 16 + ro;
        ushort4 o;
        o.x = f2b(acc[i][j][0]); o.y = f2b(acc[i][j][1]);
        o.z = f2b(acc[i][j][2]); o.w = f2b(acc[i][j][3]);
        *(ushort4*)&vtout[((size_t)bb * DIM_ + dg) * L_ + l] = o;
      }
    }
  }
}

// ---------------- proj GEMM: plain (R7 structure), f32 out + bias ----------------
// 128x128 tile, BK=32, 4 waves, 16x16x32 MFMA, gload_lds, XCD-swizzled blocks.
__global__ __launch_bounds__(256)
void gemm_proj(const ushort_t* __restrict__ A, const ushort_t* __restrict__ BT,
               float* __restrict__ Cout, const float* __restrict__ bias) {
  const int K = DIM_;
  __shared__ ushort_t As[128 * 32];
  __shared__ ushort_t Bs[128 * 32];
  const int lane = threadIdx.x & 63;
  const int wid  = threadIdx.x >> 6;
  const int wm = wid >> 1, wn = wid & 1;
  // XCD swizzle: 256 blocks (256 % 8 == 0)
  const int nwg = gridDim.x * gridDim.y;
  const int swz = xcd_swz(blockIdx.y * gridDim.x + blockIdx.x, nwg);
  const int m0 = (swz / gridDim.x) * 128, n0 = (swz % gridDim.x) * 128;
  const int ro = lane & 15, kg = lane >> 4;

  f32x4 acc[4][4] = {};

  for (int k0 = 0; k0 < K; k0 += 32) {
    const int cb = wid * 128;
#pragma unroll
    for (int j = 0; j < 2; ++j) {
      int c = cb + j * 64 + lane;
      gload_lds16(A + (size_t)(m0 + (c >> 2)) * K + k0 + (c & 3) * 8,
                  &As[(cb + j * 64) * 8]);
    }
#pragma unroll
    for (int j = 0; j < 2; ++j) {
      int c = cb + j * 64 + lane;
      gload_lds16(BT + (size_t)(n0 + (c >> 2)) * K + k0 + (c & 3) * 8,
                  &Bs[(cb + j * 64) * 8]);
    }
    __syncthreads();
    bf16x8 af[4], bfr[4];
#pragma unroll
    for (int i = 0; i < 4; ++i)
      af[i] = *(const bf16x8*)&As[(wm * 64 + i * 16 + ro) * 32 + kg * 8];
#pragma unroll
    for (int i = 0; i < 4; ++i)
      bfr[i] = *(const bf16x8*)&Bs[(wn * 64 + i * 16 + ro) * 32 + kg * 8];
#pragma unroll
    for (int i = 0; i < 4; ++i)
#pragma unroll
      for (int j = 0; j < 4; ++j)
        acc[i][j] = __builtin_amdgcn_mfma_f32_16x16x32_bf16(af[i], bfr[j],
                                                            acc[i][j], 0, 0, 0);
    __syncthreads();
  }

#pragma unroll
  for (int i = 0; i < 4; ++i)
#pragma unroll
    for (int r = 0; r < 4; ++r) {
      int row = m0 + wm * 64 + i * 16 + kg * 4 + r;
#pragma unroll
      for (int j = 0; j < 4; ++j) {
        int col = n0 + wn * 64 + j * 16 + ro;
        Cout[(size_t)row * DIM_ + col] = acc[i][j][r] + bias[col];
      }
    }
}

// ---------------- flash attention, 32x32 MFMA, joint half-tiles, K-split x2 ----------------
// SPLIT=1: grid (L/128, H, B*NSPL), half K range per block (16 tiles),
// bf16 partials + (m,l).  SPLIT=0: single pass -> bf16 O.
template <int SPLIT>
__global__ __launch_bounds__(256, 3)
void flash_attn(const ushort_t* __restrict__ qk, const ushort_t* __restrict__ vt,
                ushort_t* __restrict__ O, ushort_t* __restrict__ Opart,
                float* __restrict__ Ml) {
  const int qt = blockIdx.x, h = blockIdx.y;
  const int b  = SPLIT ? (int)(blockIdx.z >> 1) : (int)blockIdx.z;
  const int ks = SPLIT ? (int)(blockIdx.z & 1) : 0;
  const int ktBeg = SPLIT ? ks * (L_ / 64 / NSPL) : 0;   // 16 tiles per split
  const int ktEnd = SPLIT ? ktBeg + (L_ / 64 / NSPL) : (L_ / 64);
  const int lane = threadIdx.x & 63, wid = threadIdx.x >> 6;
  const int lq = lane & 31;          // q (QK) / d' (PV A) / col index
  const int hi = lane >> 5;          // lane-half: k-slice half selector
  const int q0 = qt * 128;
  const size_t tok0 = (size_t)b * L_;
  const ushort_t* qb = qk + tok0 * 2048 + h * HD_;
  const ushort_t* kb = qb + DIM_;
  const ushort_t* vb = vt + ((size_t)b * DIM_ + h * HD_) * L_;

  __shared__ ushort_t Ks[2][4096];   // [kpos 64][d 64], 16B-chunk XOR swizzle
  __shared__ ushort_t Vs[2][4096];   // [d 64][kpos 64], same swizzle

  const int srow0 = wid * 16 + (lane >> 3);
  const int sc    = (lane & 7) ^ (srow0 & 7);
  const ushort_t* kst = kb + (size_t)(ktBeg * 64 + srow0) * 2048 + sc * 8;
  const ushort_t* vst = vb + (size_t)srow0 * L_ + ktBeg * 64 + sc * 8;
  auto STAGE = [&](int bufi) {
    gload_lds16(kst,            &Ks[bufi][wid * 1024]);
    gload_lds16(kst + 8 * 2048, &Ks[bufi][wid * 1024 + 512]);
    gload_lds16(vst,            &Vs[bufi][wid * 1024]);
    gload_lds16(vst + 8 * L_,   &Vs[bufi][wid * 1024 + 512]);
    kst += 64 * 2048;
    vst += 64;
  };

  // Q fragments: B-operand of QK^T.  qf[s]: Q[q=lq][d = 16s + hi*8 + j]
  bf16x8 qf[4];
  {
    const ushort_t* gp = qb + (size_t)(q0 + wid * 32 + lq) * 2048;
#pragma unroll
    for (int s = 0; s < 4; ++s)
      qf[s] = *(const bf16x8*)(gp + s * 16 + hi * 8);
  }

  // ones A-operand: row-sum of P on the matrix pipe
  bf16x8 onesv;
#pragma unroll
  for (int i = 0; i < 8; ++i) onesv[i] = (__bf16)1.0f;

  int chs[4];
#pragma unroll
  for (int s = 0; s < 4; ++s) chs[s] = ((2 * s + hi) ^ (lq & 7)) * 8;

  f32x16 oaccT[2] = {};              // [dtile] D[row=d'][col=q=lq]
  f32x16 laccv = {};                 // ones-MFMA row-sum; only [0] consumed
  float mrow = 0.f;                  // absolute running max (shifted trigger)

  STAGE(0);
  __syncthreads();

  auto TILE = [&](int bi, bool more) {
    if (more) STAGE(bi ^ 1);
    const ushort_t* kb0 = &Ks[bi][lq * 64];
    const ushort_t* vb0 = &Vs[bi][lq * 64];

    // QK both half-tiles, C-init = -mrow: st = S - mrow (shifted domain)
    f32x16 st0, st1;
#pragma unroll
    for (int i = 0; i < 16; ++i) { st0[i] = -mrow; st1[i] = -mrow; }
    __builtin_amdgcn_s_setprio(1);
#pragma unroll
    for (int s = 0; s < 4; ++s) {
      bf16x8 kf0 = *(const bf16x8*)(kb0 + chs[s]);
      bf16x8 kf1 = *(const bf16x8*)(kb0 + 2048 + chs[s]);
      st0 = __builtin_amdgcn_mfma_f32_32x32x16_bf16(kf0, qf[s], st0, 0, 0, 0);
      st1 = __builtin_amdgcn_mfma_f32_32x32x16_bf16(kf1, qf[s], st1, 0, 0, 0);
    }
    __builtin_amdgcn_s_setprio(0);

    // joint shifted max over 32 values (max3 tree) + cross-half
    float a0 = fmax3(st0[0],  st0[1],  st0[2]);
    float a1 = fmax3(st0[3],  st0[4],  st0[5]);
    float a2 = fmax3(st0[6],  st0[7],  st0[8]);
    float a3 = fmax3(st0[9],  st0[10], st0[11]);
    float a4 = fmax3(st0[12], st0[13], st0[14]);
    float a5 = fmax3(st0[15], st1[0],  st1[1]);
    float a6 = fmax3(st1[2],  st1[3],  st1[4]);
    float a7 = fmax3(st1[5],  st1[6],  st1[7]);
    float a8 = fmax3(st1[8],  st1[9],  st1[10]);
    float a9 = fmax3(st1[11], st1[12], st1[13]);
    float aa = fmaxf(st1[14], st1[15]);
    float c0 = fmax3(a0, a1, a2);
    float c1 = fmax3(a3, a4, a5);
    float c2 = fmax3(a6, a7, a8);
    float c3 = fmax3(a9, aa, c0);
    float pm = fmax3(c1, c2, c3);
    pm = fmaxf(pm, __shfl_xor(pm, 32));

    // defer-max: rescale only when max grew by >8 over mrow (log2 domain)
    if (__any(pm > 8.f)) {
      float d = fmaxf(pm, 0.f);
      float alpha = __builtin_amdgcn_exp2f(-d);
      mrow += d;
      laccv[0] *= alpha;
#pragma unroll
      for (int dt = 0; dt < 2; ++dt)
#pragma unroll
        for (int r = 0; r < 16; ++r) oaccT[dt][r] *= alpha;
#pragma unroll
      for (int i = 0; i < 16; ++i) { st0[i] -= d; st1[i] -= d; }
    }

    // P = exp2(st), packed bf16 pairs
    unsigned pk0[8], pk1[8];
#pragma unroll
    for (int p = 0; p < 8; ++p) {
      float e0 = __builtin_amdgcn_exp2f(st0[2 * p]);
      float e1 = __builtin_amdgcn_exp2f(st0[2 * p + 1]);
      pk0[p] = (unsigned)f2b(e0) | ((unsigned)f2b(e1) << 16);
      float f0 = __builtin_amdgcn_exp2f(st1[2 * p]);
      float f1 = __builtin_amdgcn_exp2f(st1[2 * p + 1]);
      pk1[p] = (unsigned)f2b(f0) | ((unsigned)f2b(f1) << 16);
    }

    // PV: redistribute P via permlane32_swap into B-fragments
    __builtin_amdgcn_s_setprio(1);
#pragma unroll
    for (int t = 0; t < 2; ++t)
#pragma unroll
      for (int blk = 0; blk < 2; ++blk) {
        unsigned w0 = (t == 0) ? pk0[4 * blk + 0] : pk1[4 * blk + 0];
        unsigned w1 = (t == 0) ? pk0[4 * blk + 1] : pk1[4 * blk + 1];
        unsigned w2 = (t == 0) ? pk0[4 * blk + 2] : pk1[4 * blk + 2];
        unsigned w3 = (t == 0) ? pk0[4 * blk + 3] : pk1[4 * blk + 3];
        plswap(w0, w2);   // -> {j0j1, j4j5}
        plswap(w1, w3);   // -> {j2j3, j6j7}
        uint4 bw; bw.x = w0; bw.y = w1; bw.z = w2; bw.w = w3;
        bf16x8 pf = __builtin_bit_cast(bf16x8, bw);
        const int sg = 2 * t + blk;
        laccv = __builtin_amdgcn_mfma_f32_32x32x16_bf16(onesv, pf, laccv, 0, 0, 0);
#pragma unroll
        for (int dt = 0; dt < 2; ++dt) {
          bf16x8 vf = *(const bf16x8*)(vb0 + dt * 2048 + chs[sg]);
          oaccT[dt] = __builtin_amdgcn_mfma_f32_32x32x16_bf16(vf, pf,
                                                              oaccT[dt], 0, 0, 0);
        }
      }
    __builtin_amdgcn_s_setprio(0);

    __syncthreads();   // drains vmcnt: stage(next) complete; buffers safe
  };

  const int NT = ktEnd - ktBeg;      // 16 (split) or 32 (single), even
  for (int it = 0; it < NT; it += 2) {
    TILE(0, it + 1 < NT);
    TILE(1, it + 2 < NT);
  }

  const float lrow = laccv[0];
  const float linv = 1.f / lrow;
  const int tok = (int)tok0 + q0 + wid * 32 + lq;
  ushort_t* obp = (SPLIT ? Opart + (size_t)ks * M_ * DIM_ : O)
                  + (size_t)tok * DIM_ + h * HD_;
#pragma unroll
  for (int dt = 0; dt < 2; ++dt)
#pragma unroll
    for (int g4 = 0; g4 < 4; ++g4) {
      int d0 = dt * 32 + g4 * 8 + hi * 4;
      ushort4 o4;
      o4.x = f2b(oaccT[dt][4 * g4 + 0] * linv);
      o4.y = f2b(oaccT[dt][4 * g4 + 1] * linv);
      o4.z = f2b(oaccT[dt][4 * g4 + 2] * linv);
      o4.w = f2b(oaccT[dt][4 * g4 + 3] * linv);
      *(ushort4*)(obp + d0) = o4;
    }
  if (SPLIT && hi == 0) {
    float2 ml; ml.x = mrow; ml.y = lrow;
    *(float2*)&Ml[(((size_t)ks * M_ + tok) * H_ + h) * 2] = ml;
  }
}

// ---------------- combine NSPL K-split partials (bf16) -> bf16 O ----------------
// O = sum_i w_i*O_i, w_i = l_i*2^(m_i-M) / sum  (partials are normalized)
__global__ __launch_bounds__(256)
void attn_combine(const ushort_t* __restrict__ Opart, const float* __restrict__ Ml,
                  ushort_t* __restrict__ O) {
  int idx = blockIdx.x * 256 + threadIdx.x;   // 524288 threads, 8 bf16 each
  int c   = idx & 127;                        // chunk-of-8 within row
  int tok = idx >> 7;
  int h   = c >> 3;
  float2 ml[NSPL];
  float mM = -1e30f;
#pragma unroll
  for (int s = 0; s < NSPL; ++s) {
    ml[s] = *(const float2*)&Ml[(((size_t)s * M_ + tok) * H_ + h) * 2];
    mM = fmaxf(mM, ml[s].x);
  }
  float w[NSPL], sum = 0.f;
#pragma unroll
  for (int s = 0; s < NSPL; ++s) {
    w[s] = ml[s].y * __builtin_amdgcn_exp2f(ml[s].x - mM);
    sum += w[s];
  }
  float inv = 1.f / sum;
  size_t off = (size_t)tok * DIM_ + c * 8;
  float o[8] = {};
#pragma unroll
  for (int s = 0; s < NSPL; ++s) {
    uint4 a = *(const uint4*)&Opart[(size_t)s * M_ * DIM_ + off];
    float ws = w[s] * inv;
    const unsigned* pa = (const unsigned*)&a;
#pragma unroll
    for (int wd = 0; wd < 4; ++wd) {
      o[2 * wd]     += b2f((unsigned short)(pa[wd] & 0xffff)) * ws;
      o[2 * wd + 1] += b2f((unsigned short)(pa[wd] >> 16)) * ws;
    }
  }
  unsigned ow[4];
#pragma unroll
  for (int wd = 0; wd < 4; ++wd)
    ow[wd] = (unsigned)f2b(o[2 * wd]) | ((unsigned)f2b(o[2 * wd + 1]) << 16);
  uint4 ov; ov.x = ow[0]; ov.y = ow[1]; ov.z = ow[2]; ov.w = ow[3];
  *(uint4*)&O[off] = ov;
}

// ---------------- launch ----------------
extern "C" void kernel_launch(void* const* d_in, const int* in_sizes, int n_in,
                              void* d_out, int out_size, void* d_ws, size_t ws_size,
                              hipStream_t stream) {
  const float* x     = (const float*)d_in[0];
  const float* Wqkv  = (const float*)d_in[1];
  const float* qs    = (const float*)d_in[2];
  const float* ks    = (const float*)d_in[3];
  const float* Wproj = (const float*)d_in[4];
  const float* bproj = (const float*)d_in[5];
  float* out = (float*)d_out;

  char* ws = (char*)d_ws;
  ushort_t* xb     = (ushort_t*)(ws);                                  // 8 MB
  ushort_t* WqkvT  = (ushort_t*)(ws + (size_t)(8u << 20));             // 6 MB
  ushort_t* WprojT = (ushort_t*)(ws + (size_t)(14u << 20));            // 2 MB
  ushort_t* qkb    = (ushort_t*)(ws + (size_t)(16u << 20));            // 16 MB [4096][2048]
  ushort_t* vtb    = (ushort_t*)(ws + (size_t)(32u << 20));            // 8 MB  [2][1024][2048]
  float*    cosT   = (float*)(ws + (size_t)(40u << 20));               // 256 KB
  float*    sinT   = (float*)(ws + (size_t)(40u << 20) + (256u << 10));// 256 KB
  ushort_t* ob     = (ushort_t*)(ws + (size_t)(41u << 20));            // 8 MB
  ushort_t* Opart  = (ushort_t*)(ws + (size_t)(49u << 20));            // 16 MB [2][4096][1024] bf16
  float*    Ml     = (float*)(ws + (size_t)(65u << 20));               // 1 MB  [2][4096][16][2] f32

  preproc<<<5376, 256, 0, stream>>>(x, xb, Wqkv, WqkvT, Wproj, WprojT,
                                    cosT, sinT);
  gemm_qkv<<<dim3(24, 32), 256, 0, stream>>>(xb, WqkvT, qkb, vtb,
                                             qs, ks, cosT, sinT);
  if (ws_size >= ((size_t)66u << 20)) {
    flash_attn<1><<<dim3(16, 16, B_ * NSPL), 256, 0, stream>>>(qkb, vtb, nullptr,
                                                               Opart, Ml);
    attn_combine<<<2048, 256, 0, stream>>>(Opart, Ml, ob);
  } else {
    flash_attn<0><<<dim3(16, 16, 2), 256, 0, stream>>>(qkb, vtb, ob,
                                                       nullptr, nullptr);
  }
  gemm_proj<<<dim3(8, 32), 256, 0, stream>>>(ob, WprojT, out, bproj);
}

// Round 14
// 139.475 us; speedup vs baseline: 1.1113x; 1.0084x over previous
//
#include <hip/hip_runtime.h>
#include <hip/hip_bf16.h>
#include <cstdint>

#define B_   2
#define L_   2048
#define DIM_ 1024
#define H_   16
#define HD_  64
#define M_   (B_ * L_)    // 4096
#define N3_  (3 * DIM_)   // 3072
#define NSPL 2            // flash K-split factor

typedef unsigned short ushort_t;
typedef __bf16 bf16x8 __attribute__((ext_vector_type(8)));
typedef float  f32x4  __attribute__((ext_vector_type(4)));
typedef float  f32x16 __attribute__((ext_vector_type(16)));
typedef unsigned u32x2_t __attribute__((ext_vector_type(2)));

// native cast -> compiler emits v_cvt_pk_bf16_f32 for adjacent pairs (RTNE)
__device__ __forceinline__ unsigned short f2b(float f) {
  return __builtin_bit_cast(unsigned short, (__bf16)f);
}
__device__ __forceinline__ float b2f(unsigned short s) {
  unsigned u = ((unsigned)s) << 16;
  return __builtin_bit_cast(float, u);
}
__device__ __forceinline__ float fmax3(float a, float b, float c) {
  return fmaxf(fmaxf(a, b), c);   // fuses to v_max3_f32
}

// {a,b} -> a' = [a_lo | b_lo], b' = [a_hi | b_hi]  (lane halves)
__device__ __forceinline__ void plswap(unsigned &a, unsigned &b) {
#if defined(__has_builtin) && __has_builtin(__builtin_amdgcn_permlane32_swap)
  u32x2_t r = __builtin_amdgcn_permlane32_swap(a, b, false, false);
  a = r[0]; b = r[1];
#else
  unsigned sa = (unsigned)__shfl_xor((int)a, 32);
  unsigned sb = (unsigned)__shfl_xor((int)b, 32);
  bool hi = (threadIdx.x & 32) != 0;
  unsigned na = hi ? sb : a;
  unsigned nb = hi ? b : sa;
  a = na; b = nb;
#endif
}

typedef const __attribute__((address_space(1))) void* as1cp;
typedef __attribute__((address_space(3))) void* as3p;
__device__ __forceinline__ void gload_lds16(const void* g, void* l) {
  __builtin_amdgcn_global_load_lds((as1cp)g, (as3p)l, 16, 0, 0);
}

// XCD-aware bijective swizzle of a linear block id (requires nwg % 8 == 0):
// XCD j gets nwg/8 CONSECUTIVE work ids -> neighboring tiles share L2 panels.
__device__ __forceinline__ int xcd_swz(int bid, int nwg) {
  return (bid & 7) * (nwg >> 3) + (bid >> 3);
}

// ---------------- fused preprocessing ----------------
// blk [0,4096):      f32 -> bf16 convert of x (1M float4)
// blk [4096,4864):   Wqkv  f32 [1024][3072] -> bf16 [3072][1024] transpose
// blk [4864,5120):   Wproj f32 [1024][1024] -> bf16 [1024][1024] transpose
// blk [5120,5376):   rope cos/sin table [2048][32]
__global__ __launch_bounds__(256)
void preproc(const float* __restrict__ x, ushort_t* __restrict__ xb,
             const float* __restrict__ Wqkv, ushort_t* __restrict__ WqkvT,
             const float* __restrict__ Wproj, ushort_t* __restrict__ WprojT,
             float* __restrict__ cosT, float* __restrict__ sinT) {
  __shared__ float tile[64][65];
  const int blk = blockIdx.x;
  const int t = threadIdx.x;
  if (blk < 4096) {
    int i = blk * 256 + t;
    float4 v = *(const float4*)&x[(size_t)i * 4];
    ushort4 o;
    o.x = f2b(v.x); o.y = f2b(v.y); o.z = f2b(v.z); o.w = f2b(v.w);
    *(ushort4*)&xb[(size_t)i * 4] = o;
  } else if (blk < 5120) {
    const float* in;
    ushort_t* out;
    int C, bi;
    if (blk < 4864) { in = Wqkv; out = WqkvT; C = 3072; bi = blk - 4096; }
    else            { in = Wproj; out = WprojT; C = 1024; bi = blk - 4864; }
    const int nbx = C >> 6;
    const int bx = bi % nbx, by = bi / nbx;
    const int r0 = by * 64, c0 = bx * 64;
    const int R = 1024;
#pragma unroll
    for (int p = 0; p < 4; ++p) {
      int r = (t >> 4) + p * 16;
      int c = (t & 15) * 4;
      float4 v = *(const float4*)&in[(size_t)(r0 + r) * C + (c0 + c)];
      tile[r][c + 0] = v.x; tile[r][c + 1] = v.y;
      tile[r][c + 2] = v.z; tile[r][c + 3] = v.w;
    }
    __syncthreads();
#pragma unroll
    for (int p = 0; p < 4; ++p) {
      int cc = (t >> 4) + p * 16;
      int r  = (t & 15) * 4;
      ushort4 o;
      o.x = f2b(tile[r + 0][cc]); o.y = f2b(tile[r + 1][cc]);
      o.z = f2b(tile[r + 2][cc]); o.w = f2b(tile[r + 3][cc]);
      *(ushort4*)&out[(size_t)(c0 + cc) * R + (r0 + r)] = o;
    }
  } else {
    int idx = (blk - 5120) * 256 + t;   // 65536 = 2048*32
    int l = idx >> 5, d = idx & 31;
    float inv_freq = expf(-((float)(2 * d) / 64.f) * logf(10000.f));
    float ang = (float)l * inv_freq;
    cosT[idx] = cosf(ang);
    sinT[idx] = sinf(ang);
  }
}

// ---------------- QKV GEMM: 128x128 tile, BK=32 (proven R7 structure) ----------------
// 4 waves (2x2), 16x16x32 MFMA, global_load_lds staging, XCD-swizzled blocks.
// q,k cols [0,2048): fused per-head RMSNorm + RoPE in the epilogue (wave's
// 64-col slice = exactly one head; q/k split at col 1024 block-uniform);
// Q prescaled by 0.125*log2(e).  V cols [2048,3072) -> vt[b][d][l].
__global__ __launch_bounds__(256)
void gemm_qkv(const ushort_t* __restrict__ A, const ushort_t* __restrict__ BT,
              ushort_t* __restrict__ Cqk, ushort_t* __restrict__ vtout,
              const float* __restrict__ qsc_, const float* __restrict__ ksc_,
              const float* __restrict__ cosT, const float* __restrict__ sinT) {
  const int K = DIM_;
  __shared__ ushort_t As[128 * 32];
  __shared__ ushort_t Bs[128 * 32];
  const int lane = threadIdx.x & 63;
  const int wid  = threadIdx.x >> 6;
  const int wm = wid >> 1, wn = wid & 1;
  // XCD swizzle: 768 blocks (768 % 8 == 0), XCD gets 96 consecutive tiles
  const int nwg = gridDim.x * gridDim.y;
  const int swz = xcd_swz(blockIdx.y * gridDim.x + blockIdx.x, nwg);
  const int m0 = (swz / gridDim.x) * 128, n0 = (swz % gridDim.x) * 128;
  const int ro = lane & 15, kg = lane >> 4;

  f32x4 acc[4][4] = {};

  for (int k0 = 0; k0 < K; k0 += 32) {
    const int cb = wid * 128;
#pragma unroll
    for (int j = 0; j < 2; ++j) {
      int c = cb + j * 64 + lane;
      gload_lds16(A + (size_t)(m0 + (c >> 2)) * K + k0 + (c & 3) * 8,
                  &As[(cb + j * 64) * 8]);
    }
#pragma unroll
    for (int j = 0; j < 2; ++j) {
      int c = cb + j * 64 + lane;
      gload_lds16(BT + (size_t)(n0 + (c >> 2)) * K + k0 + (c & 3) * 8,
                  &Bs[(cb + j * 64) * 8]);
    }
    __syncthreads();
    bf16x8 af[4], bfr[4];
#pragma unroll
    for (int i = 0; i < 4; ++i)
      af[i] = *(const bf16x8*)&As[(wm * 64 + i * 16 + ro) * 32 + kg * 8];
#pragma unroll
    for (int i = 0; i < 4; ++i)
      bfr[i] = *(const bf16x8*)&Bs[(wn * 64 + i * 16 + ro) * 32 + kg * 8];
#pragma unroll
    for (int i = 0; i < 4; ++i)
#pragma unroll
      for (int j = 0; j < 4; ++j)
        acc[i][j] = __builtin_amdgcn_mfma_f32_16x16x32_bf16(af[i], bfr[j],
                                                            acc[i][j], 0, 0, 0);
    __syncthreads();
  }

  if (n0 < 2048) {
    // fused RMSNorm + RoPE.  d = j*16 + ro within this wave's head.
    const int ic = (n0 >= 1024);             // 0 = q, 1 = k (block-uniform)
    const float* scp = ic ? ksc_ : qsc_;
    const float qsc = ic ? 1.f : 0.125f * 1.44269504088896341f;
    float sc[4];
#pragma unroll
    for (int j = 0; j < 4; ++j) sc[j] = scp[j * 16 + ro];
#pragma unroll
    for (int i = 0; i < 4; ++i)
#pragma unroll
      for (int r = 0; r < 4; ++r) {
        int row = m0 + wm * 64 + i * 16 + kg * 4 + r;
        int l = row & (L_ - 1);
        float x0 = acc[i][0][r], x1 = acc[i][1][r];
        float x2 = acc[i][2][r], x3 = acc[i][3][r];
        float ss = x0 * x0 + x1 * x1 + x2 * x2 + x3 * x3;
        ss += __shfl_xor(ss, 1); ss += __shfl_xor(ss, 2);
        ss += __shfl_xor(ss, 4); ss += __shfl_xor(ss, 8);
        float inv = rsqrtf(ss * (1.f / 64.f) + 1e-6f);
        x0 *= inv * sc[0]; x1 *= inv * sc[1];
        x2 *= inv * sc[2]; x3 *= inv * sc[3];
        float cv0 = cosT[l * 32 + ro],      sv0 = sinT[l * 32 + ro];
        float cv1 = cosT[l * 32 + 16 + ro], sv1 = sinT[l * 32 + 16 + ro];
        float o0 = (x0 * cv0 - x2 * sv0) * qsc;
        float o1 = (x1 * cv1 - x3 * sv1) * qsc;
        float o2 = (x2 * cv0 + x0 * sv0) * qsc;
        float o3 = (x3 * cv1 + x1 * sv1) * qsc;
        ushort_t* cp = Cqk + (size_t)row * 2048 + n0 + wn * 64 + ro;
        cp[0]  = f2b(o0);
        cp[16] = f2b(o1);
        cp[32] = f2b(o2);
        cp[48] = f2b(o3);
      }
  } else {
    // V columns -> vt[b][dg][l], 4 consecutive l per lane packed
#pragma unroll
    for (int i = 0; i < 4; ++i) {
      int rowb = m0 + wm * 64 + i * 16 + kg * 4;
      int bb = rowb >> 11, l = rowb & (L_ - 1);
#pragma unroll
      for (int j = 0; j < 4; ++j) {
        int dg = (n0 - 2048) + wn * 64 + j * 16 + ro;
        ushort4 o;
        o.x = f2b(acc[i][j][0]); o.y = f2b(acc[i][j][1]);
        o.z = f2b(acc[i][j][2]); o.w = f2b(acc[i][j][3]);
        *(ushort4*)&vtout[((size_t)bb * DIM_ + dg) * L_ + l] = o;
      }
    }
  }
}

// ---------------- proj GEMM: plain (R7 structure), f32 out + bias ----------------
// 128x128 tile, BK=32, 4 waves, 16x16x32 MFMA, gload_lds, XCD-swizzled blocks.
__global__ __launch_bounds__(256)
void gemm_proj(const ushort_t* __restrict__ A, const ushort_t* __restrict__ BT,
               float* __restrict__ Cout, const float* __restrict__ bias) {
  const int K = DIM_;
  __shared__ ushort_t As[128 * 32];
  __shared__ ushort_t Bs[128 * 32];
  const int lane = threadIdx.x & 63;
  const int wid  = threadIdx.x >> 6;
  const int wm = wid >> 1, wn = wid & 1;
  // XCD swizzle: 256 blocks (256 % 8 == 0)
  const int nwg = gridDim.x * gridDim.y;
  const int swz = xcd_swz(blockIdx.y * gridDim.x + blockIdx.x, nwg);
  const int m0 = (swz / gridDim.x) * 128, n0 = (swz % gridDim.x) * 128;
  const int ro = lane & 15, kg = lane >> 4;

  f32x4 acc[4][4] = {};

  for (int k0 = 0; k0 < K; k0 += 32) {
    const int cb = wid * 128;
#pragma unroll
    for (int j = 0; j < 2; ++j) {
      int c = cb + j * 64 + lane;
      gload_lds16(A + (size_t)(m0 + (c >> 2)) * K + k0 + (c & 3) * 8,
                  &As[(cb + j * 64) * 8]);
    }
#pragma unroll
    for (int j = 0; j < 2; ++j) {
      int c = cb + j * 64 + lane;
      gload_lds16(BT + (size_t)(n0 + (c >> 2)) * K + k0 + (c & 3) * 8,
                  &Bs[(cb + j * 64) * 8]);
    }
    __syncthreads();
    bf16x8 af[4], bfr[4];
#pragma unroll
    for (int i = 0; i < 4; ++i)
      af[i] = *(const bf16x8*)&As[(wm * 64 + i * 16 + ro) * 32 + kg * 8];
#pragma unroll
    for (int i = 0; i < 4; ++i)
      bfr[i] = *(const bf16x8*)&Bs[(wn * 64 + i * 16 + ro) * 32 + kg * 8];
#pragma unroll
    for (int i = 0; i < 4; ++i)
#pragma unroll
      for (int j = 0; j < 4; ++j)
        acc[i][j] = __builtin_amdgcn_mfma_f32_16x16x32_bf16(af[i], bfr[j],
                                                            acc[i][j], 0, 0, 0);
    __syncthreads();
  }

#pragma unroll
  for (int i = 0; i < 4; ++i)
#pragma unroll
    for (int r = 0; r < 4; ++r) {
      int row = m0 + wm * 64 + i * 16 + kg * 4 + r;
#pragma unroll
      for (int j = 0; j < 4; ++j) {
        int col = n0 + wn * 64 + j * 16 + ro;
        Cout[(size_t)row * DIM_ + col] = acc[i][j][r] + bias[col];
      }
    }
}

// ---------------- flash attention, 32x32 MFMA, joint half-tiles, K-split x2 ----------------
// SPLIT=1: grid (L/128, H, B*NSPL), half K range per block (16 tiles),
// bf16 partials + (m,l).  SPLIT=0: single pass -> bf16 O.
// Register diet for 4 waves/SIMD (launch_bounds(256,4), ~128-reg budget):
// VALU row-sum (no laccv ones-MFMA) -> whole 1024-block grid co-resident,
// no 768+256 scheduling tail.
template <int SPLIT>
__global__ __launch_bounds__(256, 4)
void flash_attn(const ushort_t* __restrict__ qk, const ushort_t* __restrict__ vt,
                ushort_t* __restrict__ O, ushort_t* __restrict__ Opart,
                float* __restrict__ Ml) {
  const int qt = blockIdx.x, h = blockIdx.y;
  const int b  = SPLIT ? (int)(blockIdx.z >> 1) : (int)blockIdx.z;
  const int ks = SPLIT ? (int)(blockIdx.z & 1) : 0;
  const int ktBeg = SPLIT ? ks * (L_ / 64 / NSPL) : 0;   // 16 tiles per split
  const int ktEnd = SPLIT ? ktBeg + (L_ / 64 / NSPL) : (L_ / 64);
  const int lane = threadIdx.x & 63, wid = threadIdx.x >> 6;
  const int lq = lane & 31;          // q (QK) / d' (PV A) / col index
  const int hi = lane >> 5;          // lane-half: k-slice half selector
  const int q0 = qt * 128;
  const size_t tok0 = (size_t)b * L_;
  const ushort_t* qb = qk + tok0 * 2048 + h * HD_;
  const ushort_t* kb = qb + DIM_;
  const ushort_t* vb = vt + ((size_t)b * DIM_ + h * HD_) * L_;

  __shared__ ushort_t Ks[2][4096];   // [kpos 64][d 64], 16B-chunk XOR swizzle
  __shared__ ushort_t Vs[2][4096];   // [d 64][kpos 64], same swizzle

  const int srow0 = wid * 16 + (lane >> 3);
  const int sc    = (lane & 7) ^ (srow0 & 7);
  const ushort_t* kst = kb + (size_t)(ktBeg * 64 + srow0) * 2048 + sc * 8;
  const ushort_t* vst = vb + (size_t)srow0 * L_ + ktBeg * 64 + sc * 8;
  auto STAGE = [&](int bufi) {
    gload_lds16(kst,            &Ks[bufi][wid * 1024]);
    gload_lds16(kst + 8 * 2048, &Ks[bufi][wid * 1024 + 512]);
    gload_lds16(vst,            &Vs[bufi][wid * 1024]);
    gload_lds16(vst + 8 * L_,   &Vs[bufi][wid * 1024 + 512]);
    kst += 64 * 2048;
    vst += 64;
  };

  // Q fragments: B-operand of QK^T.  qf[s]: Q[q=lq][d = 16s + hi*8 + j]
  bf16x8 qf[4];
  {
    const ushort_t* gp = qb + (size_t)(q0 + wid * 32 + lq) * 2048;
#pragma unroll
    for (int s = 0; s < 4; ++s)
      qf[s] = *(const bf16x8*)(gp + s * 16 + hi * 8);
  }

  int chs[4];
#pragma unroll
  for (int s = 0; s < 4; ++s) chs[s] = ((2 * s + hi) ^ (lq & 7)) * 8;

  f32x16 oaccT[2] = {};              // [dtile] D[row=d'][col=q=lq]
  float mrow = 0.f;                  // absolute running max (shifted trigger)
  float lrow = 0.f;                  // per-lane half row-sum (cross-half at end)

  STAGE(0);
  __syncthreads();

  auto TILE = [&](int bi, bool more) {
    if (more) STAGE(bi ^ 1);
    const ushort_t* kb0 = &Ks[bi][lq * 64];
    const ushort_t* vb0 = &Vs[bi][lq * 64];

    // QK both half-tiles, C-init = -mrow: st = S - mrow (shifted domain)
    f32x16 st0, st1;
#pragma unroll
    for (int i = 0; i < 16; ++i) { st0[i] = -mrow; st1[i] = -mrow; }
    __builtin_amdgcn_s_setprio(1);
#pragma unroll
    for (int s = 0; s < 4; ++s) {
      bf16x8 kf0 = *(const bf16x8*)(kb0 + chs[s]);
      bf16x8 kf1 = *(const bf16x8*)(kb0 + 2048 + chs[s]);
      st0 = __builtin_amdgcn_mfma_f32_32x32x16_bf16(kf0, qf[s], st0, 0, 0, 0);
      st1 = __builtin_amdgcn_mfma_f32_32x32x16_bf16(kf1, qf[s], st1, 0, 0, 0);
    }
    __builtin_amdgcn_s_setprio(0);

    // joint shifted max over 32 values (max3 tree) + cross-half
    float a0 = fmax3(st0[0],  st0[1],  st0[2]);
    float a1 = fmax3(st0[3],  st0[4],  st0[5]);
    float a2 = fmax3(st0[6],  st0[7],  st0[8]);
    float a3 = fmax3(st0[9],  st0[10], st0[11]);
    float a4 = fmax3(st0[12], st0[13], st0[14]);
    float a5 = fmax3(st0[15], st1[0],  st1[1]);
    float a6 = fmax3(st1[2],  st1[3],  st1[4]);
    float a7 = fmax3(st1[5],  st1[6],  st1[7]);
    float a8 = fmax3(st1[8],  st1[9],  st1[10]);
    float a9 = fmax3(st1[11], st1[12], st1[13]);
    float aa = fmaxf(st1[14], st1[15]);
    float c0 = fmax3(a0, a1, a2);
    float c1 = fmax3(a3, a4, a5);
    float c2 = fmax3(a6, a7, a8);
    float c3 = fmax3(a9, aa, c0);
    float pm = fmax3(c1, c2, c3);
    pm = fmaxf(pm, __shfl_xor(pm, 32));

    // defer-max: rescale only when max grew by >8 over mrow (log2 domain)
    if (__any(pm > 8.f)) {
      float d = fmaxf(pm, 0.f);
      float alpha = __builtin_amdgcn_exp2f(-d);
      mrow += d;
      lrow *= alpha;
#pragma unroll
      for (int dt = 0; dt < 2; ++dt)
#pragma unroll
        for (int r = 0; r < 16; ++r) oaccT[dt][r] *= alpha;
#pragma unroll
      for (int i = 0; i < 16; ++i) { st0[i] -= d; st1[i] -= d; }
    }

    // P = exp2(st), packed bf16 pairs + VALU row-sum (4 partials for ILP)
    unsigned pk0[8], pk1[8];
    float rs0 = 0.f, rs1 = 0.f, rs2 = 0.f, rs3 = 0.f;
#pragma unroll
    for (int p = 0; p < 8; ++p) {
      float e0 = __builtin_amdgcn_exp2f(st0[2 * p]);
      float e1 = __builtin_amdgcn_exp2f(st0[2 * p + 1]);
      rs0 += e0; rs1 += e1;
      pk0[p] = (unsigned)f2b(e0) | ((unsigned)f2b(e1) << 16);
      float f0 = __builtin_amdgcn_exp2f(st1[2 * p]);
      float f1 = __builtin_amdgcn_exp2f(st1[2 * p + 1]);
      rs2 += f0; rs3 += f1;
      pk1[p] = (unsigned)f2b(f0) | ((unsigned)f2b(f1) << 16);
    }
    lrow += (rs0 + rs1) + (rs2 + rs3);

    // PV: redistribute P via permlane32_swap into B-fragments
    __builtin_amdgcn_s_setprio(1);
#pragma unroll
    for (int t = 0; t < 2; ++t)
#pragma unroll
      for (int blk = 0; blk < 2; ++blk) {
        unsigned w0 = (t == 0) ? pk0[4 * blk + 0] : pk1[4 * blk + 0];
        unsigned w1 = (t == 0) ? pk0[4 * blk + 1] : pk1[4 * blk + 1];
        unsigned w2 = (t == 0) ? pk0[4 * blk + 2] : pk1[4 * blk + 2];
        unsigned w3 = (t == 0) ? pk0[4 * blk + 3] : pk1[4 * blk + 3];
        plswap(w0, w2);   // -> {j0j1, j4j5}
        plswap(w1, w3);   // -> {j2j3, j6j7}
        uint4 bw; bw.x = w0; bw.y = w1; bw.z = w2; bw.w = w3;
        bf16x8 pf = __builtin_bit_cast(bf16x8, bw);
        const int sg = 2 * t + blk;
#pragma unroll
        for (int dt = 0; dt < 2; ++dt) {
          bf16x8 vf = *(const bf16x8*)(vb0 + dt * 2048 + chs[sg]);
          oaccT[dt] = __builtin_amdgcn_mfma_f32_32x32x16_bf16(vf, pf,
                                                              oaccT[dt], 0, 0, 0);
        }
      }
    __builtin_amdgcn_s_setprio(0);

    __syncthreads();   // drains vmcnt: stage(next) complete; buffers safe
  };

  const int NT = ktEnd - ktBeg;      // 16 (split) or 32 (single), even
  for (int it = 0; it < NT; it += 2) {
    TILE(0, it + 1 < NT);
    TILE(1, it + 2 < NT);
  }

  // epilogue: lane-local (q = lq); full row-sum needs cross-half add
  lrow += __shfl_xor(lrow, 32);
  const float linv = 1.f / lrow;
  const int tok = (int)tok0 + q0 + wid * 32 + lq;
  ushort_t* obp = (SPLIT ? Opart + (size_t)ks * M_ * DIM_ : O)
                  + (size_t)tok * DIM_ + h * HD_;
#pragma unroll
  for (int dt = 0; dt < 2; ++dt)
#pragma unroll
    for (int g4 = 0; g4 < 4; ++g4) {
      int d0 = dt * 32 + g4 * 8 + hi * 4;
      ushort4 o4;
      o4.x = f2b(oaccT[dt][4 * g4 + 0] * linv);
      o4.y = f2b(oaccT[dt][4 * g4 + 1] * linv);
      o4.z = f2b(oaccT[dt][4 * g4 + 2] * linv);
      o4.w = f2b(oaccT[dt][4 * g4 + 3] * linv);
      *(ushort4*)(obp + d0) = o4;
    }
  if (SPLIT && hi == 0) {
    float2 ml; ml.x = mrow; ml.y = lrow;
    *(float2*)&Ml[(((size_t)ks * M_ + tok) * H_ + h) * 2] = ml;
  }
}

// ---------------- combine NSPL K-split partials (bf16) -> bf16 O ----------------
// O = sum_i w_i*O_i, w_i = l_i*2^(m_i-M) / sum  (partials are normalized)
__global__ __launch_bounds__(256)
void attn_combine(const ushort_t* __restrict__ Opart, const float* __restrict__ Ml,
                  ushort_t* __restrict__ O) {
  int idx = blockIdx.x * 256 + threadIdx.x;   // 524288 threads, 8 bf16 each
  int c   = idx & 127;                        // chunk-of-8 within row
  int tok = idx >> 7;
  int h   = c >> 3;
  float2 ml[NSPL];
  float mM = -1e30f;
#pragma unroll
  for (int s = 0; s < NSPL; ++s) {
    ml[s] = *(const float2*)&Ml[(((size_t)s * M_ + tok) * H_ + h) * 2];
    mM = fmaxf(mM, ml[s].x);
  }
  float w[NSPL], sum = 0.f;
#pragma unroll
  for (int s = 0; s < NSPL; ++s) {
    w[s] = ml[s].y * __builtin_amdgcn_exp2f(ml[s].x - mM);
    sum += w[s];
  }
  float inv = 1.f / sum;
  size_t off = (size_t)tok * DIM_ + c * 8;
  float o[8] = {};
#pragma unroll
  for (int s = 0; s < NSPL; ++s) {
    uint4 a = *(const uint4*)&Opart[(size_t)s * M_ * DIM_ + off];
    float ws = w[s] * inv;
    const unsigned* pa = (const unsigned*)&a;
#pragma unroll
    for (int wd = 0; wd < 4; ++wd) {
      o[2 * wd]     += b2f((unsigned short)(pa[wd] & 0xffff)) * ws;
      o[2 * wd + 1] += b2f((unsigned short)(pa[wd] >> 16)) * ws;
    }
  }
  unsigned ow[4];
#pragma unroll
  for (int wd = 0; wd < 4; ++wd)
    ow[wd] = (unsigned)f2b(o[2 * wd]) | ((unsigned)f2b(o[2 * wd + 1]) << 16);
  uint4 ov; ov.x = ow[0]; ov.y = ow[1]; ov.z = ow[2]; ov.w = ow[3];
  *(uint4*)&O[off] = ov;
}

// ---------------- launch ----------------
extern "C" void kernel_launch(void* const* d_in, const int* in_sizes, int n_in,
                              void* d_out, int out_size, void* d_ws, size_t ws_size,
                              hipStream_t stream) {
  const float* x     = (const float*)d_in[0];
  const float* Wqkv  = (const float*)d_in[1];
  const float* qs    = (const float*)d_in[2];
  const float* ks    = (const float*)d_in[3];
  const float* Wproj = (const float*)d_in[4];
  const float* bproj = (const float*)d_in[5];
  float* out = (float*)d_out;

  char* ws = (char*)d_ws;
  ushort_t* xb     = (ushort_t*)(ws);                                  // 8 MB
  ushort_t* WqkvT  = (ushort_t*)(ws + (size_t)(8u << 20));             // 6 MB
  ushort_t* WprojT = (ushort_t*)(ws + (size_t)(14u << 20));            // 2 MB
  ushort_t* qkb    = (ushort_t*)(ws + (size_t)(16u << 20));            // 16 MB [4096][2048]
  ushort_t* vtb    = (ushort_t*)(ws + (size_t)(32u << 20));            // 8 MB  [2][1024][2048]
  float*    cosT   = (float*)(ws + (size_t)(40u << 20));               // 256 KB
  float*    sinT   = (float*)(ws + (size_t)(40u << 20) + (256u << 10));// 256 KB
  ushort_t* ob     = (ushort_t*)(ws + (size_t)(41u << 20));            // 8 MB
  ushort_t* Opart  = (ushort_t*)(ws + (size_t)(49u << 20));            // 16 MB [2][4096][1024] bf16
  float*    Ml     = (float*)(ws + (size_t)(65u << 20));               // 1 MB  [2][4096][16][2] f32

  preproc<<<5376, 256, 0, stream>>>(x, xb, Wqkv, WqkvT, Wproj, WprojT,
                                    cosT, sinT);
  gemm_qkv<<<dim3(24, 32), 256, 0, stream>>>(xb, WqkvT, qkb, vtb,
                                             qs, ks, cosT, sinT);
  if (ws_size >= ((size_t)66u << 20)) {
    flash_attn<1><<<dim3(16, 16, B_ * NSPL), 256, 0, stream>>>(qkb, vtb, nullptr,
                                                               Opart, Ml);
    attn_combine<<<2048, 256, 0, stream>>>(Opart, Ml, ob);
  } else {
    flash_attn<0><<<dim3(16, 16, 2), 256, 0, stream>>>(qkb, vtb, ob,
                                                       nullptr, nullptr);
  }
  gemm_proj<<<dim3(8, 32), 256, 0, stream>>>(ob, WprojT, out, bproj);
}

// Round 15
// 138.431 us; speedup vs baseline: 1.1196x; 1.0075x over previous
//
#include <hip/hip_runtime.h>
#include <hip/hip_bf16.h>
#include <cstdint>

#define B_   2
#define L_   2048
#define DIM_ 1024
#define H_   16
#define HD_  64
#define M_   (B_ * L_)    // 4096
#define N3_  (3 * DIM_)   // 3072
#define NSPL 2            // flash K-split factor

typedef unsigned short ushort_t;
typedef __bf16 bf16x8 __attribute__((ext_vector_type(8)));
typedef float  f32x4  __attribute__((ext_vector_type(4)));
typedef float  f32x16 __attribute__((ext_vector_type(16)));
typedef unsigned u32x2_t __attribute__((ext_vector_type(2)));

// native cast -> compiler emits v_cvt_pk_bf16_f32 for adjacent pairs (RTNE)
__device__ __forceinline__ unsigned short f2b(float f) {
  return __builtin_bit_cast(unsigned short, (__bf16)f);
}
__device__ __forceinline__ float b2f(unsigned short s) {
  unsigned u = ((unsigned)s) << 16;
  return __builtin_bit_cast(float, u);
}
__device__ __forceinline__ float fmax3(float a, float b, float c) {
  return fmaxf(fmaxf(a, b), c);   // fuses to v_max3_f32
}

// {a,b} -> a' = [a_lo | b_lo], b' = [a_hi | b_hi]  (lane halves)
__device__ __forceinline__ void plswap(unsigned &a, unsigned &b) {
#if defined(__has_builtin) && __has_builtin(__builtin_amdgcn_permlane32_swap)
  u32x2_t r = __builtin_amdgcn_permlane32_swap(a, b, false, false);
  a = r[0]; b = r[1];
#else
  unsigned sa = (unsigned)__shfl_xor((int)a, 32);
  unsigned sb = (unsigned)__shfl_xor((int)b, 32);
  bool hi = (threadIdx.x & 32) != 0;
  unsigned na = hi ? sb : a;
  unsigned nb = hi ? b : sa;
  a = na; b = nb;
#endif
}

typedef const __attribute__((address_space(1))) void* as1cp;
typedef __attribute__((address_space(3))) void* as3p;
__device__ __forceinline__ void gload_lds16(const void* g, void* l) {
  __builtin_amdgcn_global_load_lds((as1cp)g, (as3p)l, 16, 0, 0);
}

// XCD-aware bijective swizzle of a linear block id (requires nwg % 8 == 0):
// XCD j gets nwg/8 CONSECUTIVE work ids -> neighboring tiles share L2 panels.
__device__ __forceinline__ int xcd_swz(int bid, int nwg) {
  return (bid & 7) * (nwg >> 3) + (bid >> 3);
}

// ---------------- fused preprocessing ----------------
// blk [0,4096):      f32 -> bf16 convert of x (1M float4)
// blk [4096,4864):   Wqkv  f32 [1024][3072] -> bf16 [3072][1024] transpose
// blk [4864,5120):   Wproj f32 [1024][1024] -> bf16 [1024][1024] transpose
// blk [5120,5376):   rope cos/sin table [2048][32]
__global__ __launch_bounds__(256)
void preproc(const float* __restrict__ x, ushort_t* __restrict__ xb,
             const float* __restrict__ Wqkv, ushort_t* __restrict__ WqkvT,
             const float* __restrict__ Wproj, ushort_t* __restrict__ WprojT,
             float* __restrict__ cosT, float* __restrict__ sinT) {
  __shared__ float tile[64][65];
  const int blk = blockIdx.x;
  const int t = threadIdx.x;
  if (blk < 4096) {
    int i = blk * 256 + t;
    float4 v = *(const float4*)&x[(size_t)i * 4];
    ushort4 o;
    o.x = f2b(v.x); o.y = f2b(v.y); o.z = f2b(v.z); o.w = f2b(v.w);
    *(ushort4*)&xb[(size_t)i * 4] = o;
  } else if (blk < 5120) {
    const float* in;
    ushort_t* out;
    int C, bi;
    if (blk < 4864) { in = Wqkv; out = WqkvT; C = 3072; bi = blk - 4096; }
    else            { in = Wproj; out = WprojT; C = 1024; bi = blk - 4864; }
    const int nbx = C >> 6;
    const int bx = bi % nbx, by = bi / nbx;
    const int r0 = by * 64, c0 = bx * 64;
    const int R = 1024;
#pragma unroll
    for (int p = 0; p < 4; ++p) {
      int r = (t >> 4) + p * 16;
      int c = (t & 15) * 4;
      float4 v = *(const float4*)&in[(size_t)(r0 + r) * C + (c0 + c)];
      tile[r][c + 0] = v.x; tile[r][c + 1] = v.y;
      tile[r][c + 2] = v.z; tile[r][c + 3] = v.w;
    }
    __syncthreads();
#pragma unroll
    for (int p = 0; p < 4; ++p) {
      int cc = (t >> 4) + p * 16;
      int r  = (t & 15) * 4;
      ushort4 o;
      o.x = f2b(tile[r + 0][cc]); o.y = f2b(tile[r + 1][cc]);
      o.z = f2b(tile[r + 2][cc]); o.w = f2b(tile[r + 3][cc]);
      *(ushort4*)&out[(size_t)(c0 + cc) * R + (r0 + r)] = o;
    }
  } else {
    int idx = (blk - 5120) * 256 + t;   // 65536 = 2048*32
    int l = idx >> 5, d = idx & 31;
    float inv_freq = expf(-((float)(2 * d) / 64.f) * logf(10000.f));
    float ang = (float)l * inv_freq;
    cosT[idx] = cosf(ang);
    sinT[idx] = sinf(ang);
  }
}

// ---------------- QKV GEMM: 128x128 tile, BK=32 (proven R7 structure) ----------------
// 4 waves (2x2), 16x16x32 MFMA, global_load_lds staging, XCD-swizzled blocks.
// q,k cols [0,2048): fused per-head RMSNorm + RoPE in the epilogue (wave's
// 64-col slice = exactly one head; q/k split at col 1024 block-uniform);
// Q prescaled by 0.125*log2(e).  V cols [2048,3072) -> vt[b][d][l].
__global__ __launch_bounds__(256)
void gemm_qkv(const ushort_t* __restrict__ A, const ushort_t* __restrict__ BT,
              ushort_t* __restrict__ Cqk, ushort_t* __restrict__ vtout,
              const float* __restrict__ qsc_, const float* __restrict__ ksc_,
              const float* __restrict__ cosT, const float* __restrict__ sinT) {
  const int K = DIM_;
  __shared__ ushort_t As[128 * 32];
  __shared__ ushort_t Bs[128 * 32];
  const int lane = threadIdx.x & 63;
  const int wid  = threadIdx.x >> 6;
  const int wm = wid >> 1, wn = wid & 1;
  // XCD swizzle: 768 blocks (768 % 8 == 0), XCD gets 96 consecutive tiles
  const int nwg = gridDim.x * gridDim.y;
  const int swz = xcd_swz(blockIdx.y * gridDim.x + blockIdx.x, nwg);
  const int m0 = (swz / gridDim.x) * 128, n0 = (swz % gridDim.x) * 128;
  const int ro = lane & 15, kg = lane >> 4;

  f32x4 acc[4][4] = {};

  for (int k0 = 0; k0 < K; k0 += 32) {
    const int cb = wid * 128;
#pragma unroll
    for (int j = 0; j < 2; ++j) {
      int c = cb + j * 64 + lane;
      gload_lds16(A + (size_t)(m0 + (c >> 2)) * K + k0 + (c & 3) * 8,
                  &As[(cb + j * 64) * 8]);
    }
#pragma unroll
    for (int j = 0; j < 2; ++j) {
      int c = cb + j * 64 + lane;
      gload_lds16(BT + (size_t)(n0 + (c >> 2)) * K + k0 + (c & 3) * 8,
                  &Bs[(cb + j * 64) * 8]);
    }
    __syncthreads();
    bf16x8 af[4], bfr[4];
#pragma unroll
    for (int i = 0; i < 4; ++i)
      af[i] = *(const bf16x8*)&As[(wm * 64 + i * 16 + ro) * 32 + kg * 8];
#pragma unroll
    for (int i = 0; i < 4; ++i)
      bfr[i] = *(const bf16x8*)&Bs[(wn * 64 + i * 16 + ro) * 32 + kg * 8];
#pragma unroll
    for (int i = 0; i < 4; ++i)
#pragma unroll
      for (int j = 0; j < 4; ++j)
        acc[i][j] = __builtin_amdgcn_mfma_f32_16x16x32_bf16(af[i], bfr[j],
                                                            acc[i][j], 0, 0, 0);
    __syncthreads();
  }

  if (n0 < 2048) {
    // fused RMSNorm + RoPE.  d = j*16 + ro within this wave's head.
    const int ic = (n0 >= 1024);             // 0 = q, 1 = k (block-uniform)
    const float* scp = ic ? ksc_ : qsc_;
    const float qsc = ic ? 1.f : 0.125f * 1.44269504088896341f;
    float sc[4];
#pragma unroll
    for (int j = 0; j < 4; ++j) sc[j] = scp[j * 16 + ro];
#pragma unroll
    for (int i = 0; i < 4; ++i)
#pragma unroll
      for (int r = 0; r < 4; ++r) {
        int row = m0 + wm * 64 + i * 16 + kg * 4 + r;
        int l = row & (L_ - 1);
        float x0 = acc[i][0][r], x1 = acc[i][1][r];
        float x2 = acc[i][2][r], x3 = acc[i][3][r];
        float ss = x0 * x0 + x1 * x1 + x2 * x2 + x3 * x3;
        ss += __shfl_xor(ss, 1); ss += __shfl_xor(ss, 2);
        ss += __shfl_xor(ss, 4); ss += __shfl_xor(ss, 8);
        float inv = rsqrtf(ss * (1.f / 64.f) + 1e-6f);
        x0 *= inv * sc[0]; x1 *= inv * sc[1];
        x2 *= inv * sc[2]; x3 *= inv * sc[3];
        float cv0 = cosT[l * 32 + ro],      sv0 = sinT[l * 32 + ro];
        float cv1 = cosT[l * 32 + 16 + ro], sv1 = sinT[l * 32 + 16 + ro];
        float o0 = (x0 * cv0 - x2 * sv0) * qsc;
        float o1 = (x1 * cv1 - x3 * sv1) * qsc;
        float o2 = (x2 * cv0 + x0 * sv0) * qsc;
        float o3 = (x3 * cv1 + x1 * sv1) * qsc;
        ushort_t* cp = Cqk + (size_t)row * 2048 + n0 + wn * 64 + ro;
        cp[0]  = f2b(o0);
        cp[16] = f2b(o1);
        cp[32] = f2b(o2);
        cp[48] = f2b(o3);
      }
  } else {
    // V columns -> vt[b][dg][l], 4 consecutive l per lane packed
#pragma unroll
    for (int i = 0; i < 4; ++i) {
      int rowb = m0 + wm * 64 + i * 16 + kg * 4;
      int bb = rowb >> 11, l = rowb & (L_ - 1);
#pragma unroll
      for (int j = 0; j < 4; ++j) {
        int dg = (n0 - 2048) + wn * 64 + j * 16 + ro;
        ushort4 o;
        o.x = f2b(acc[i][j][0]); o.y = f2b(acc[i][j][1]);
        o.z = f2b(acc[i][j][2]); o.w = f2b(acc[i][j][3]);
        *(ushort4*)&vtout[((size_t)bb * DIM_ + dg) * L_ + l] = o;
      }
    }
  }
}

// ---------------- proj GEMM: plain (R7 structure), f32 out + bias ----------------
// 128x128 tile, BK=32, 4 waves, 16x16x32 MFMA, gload_lds, XCD-swizzled blocks.
__global__ __launch_bounds__(256)
void gemm_proj(const ushort_t* __restrict__ A, const ushort_t* __restrict__ BT,
               float* __restrict__ Cout, const float* __restrict__ bias) {
  const int K = DIM_;
  __shared__ ushort_t As[128 * 32];
  __shared__ ushort_t Bs[128 * 32];
  const int lane = threadIdx.x & 63;
  const int wid  = threadIdx.x >> 6;
  const int wm = wid >> 1, wn = wid & 1;
  // XCD swizzle: 256 blocks (256 % 8 == 0)
  const int nwg = gridDim.x * gridDim.y;
  const int swz = xcd_swz(blockIdx.y * gridDim.x + blockIdx.x, nwg);
  const int m0 = (swz / gridDim.x) * 128, n0 = (swz % gridDim.x) * 128;
  const int ro = lane & 15, kg = lane >> 4;

  f32x4 acc[4][4] = {};

  for (int k0 = 0; k0 < K; k0 += 32) {
    const int cb = wid * 128;
#pragma unroll
    for (int j = 0; j < 2; ++j) {
      int c = cb + j * 64 + lane;
      gload_lds16(A + (size_t)(m0 + (c >> 2)) * K + k0 + (c & 3) * 8,
                  &As[(cb + j * 64) * 8]);
    }
#pragma unroll
    for (int j = 0; j < 2; ++j) {
      int c = cb + j * 64 + lane;
      gload_lds16(BT + (size_t)(n0 + (c >> 2)) * K + k0 + (c & 3) * 8,
                  &Bs[(cb + j * 64) * 8]);
    }
    __syncthreads();
    bf16x8 af[4], bfr[4];
#pragma unroll
    for (int i = 0; i < 4; ++i)
      af[i] = *(const bf16x8*)&As[(wm * 64 + i * 16 + ro) * 32 + kg * 8];
#pragma unroll
    for (int i = 0; i < 4; ++i)
      bfr[i] = *(const bf16x8*)&Bs[(wn * 64 + i * 16 + ro) * 32 + kg * 8];
#pragma unroll
    for (int i = 0; i < 4; ++i)
#pragma unroll
      for (int j = 0; j < 4; ++j)
        acc[i][j] = __builtin_amdgcn_mfma_f32_16x16x32_bf16(af[i], bfr[j],
                                                            acc[i][j], 0, 0, 0);
    __syncthreads();
  }

#pragma unroll
  for (int i = 0; i < 4; ++i)
#pragma unroll
    for (int r = 0; r < 4; ++r) {
      int row = m0 + wm * 64 + i * 16 + kg * 4 + r;
#pragma unroll
      for (int j = 0; j < 4; ++j) {
        int col = n0 + wn * 64 + j * 16 + ro;
        Cout[(size_t)row * DIM_ + col] = acc[i][j][r] + bias[col];
      }
    }
}

// ---------------- flash attention, 32x32 MFMA, joint half-tiles, K-split x2 ----------------
// SPLIT=1: grid (L/128, H, B*NSPL), half K range per block (16 tiles),
// bf16 partials + (m,l).  SPLIT=0: single pass -> bf16 O.
// XCD-swizzled block mapping: the 16 q-tile blocks sharing one (h,b,ks)
// K/V panel (256 KB) are placed on the SAME XCD -> each panel L2-fills
// once per chip instead of 8x (FETCH was 2.9x input without this).
// launch_bounds(256,4) + VALU row-sum (register diet, R14).
template <int SPLIT>
__global__ __launch_bounds__(256, 4)
void flash_attn(const ushort_t* __restrict__ qk, const ushort_t* __restrict__ vt,
                ushort_t* __restrict__ O, ushort_t* __restrict__ Opart,
                float* __restrict__ Ml) {
  // bijective XCD swizzle of the whole grid (nwg % 8 == 0 in both modes)
  const int nwg = gridDim.x * gridDim.y * gridDim.z;
  int w = ((int)blockIdx.z * gridDim.y + (int)blockIdx.y) * gridDim.x
          + (int)blockIdx.x;
  w = xcd_swz(w, nwg);
  const int qt = w & 15;
  const int h  = (w >> 4) & 15;
  const int bz = w >> 8;
  const int b  = SPLIT ? (bz >> 1) : bz;
  const int ks = SPLIT ? (bz & 1) : 0;
  const int ktBeg = SPLIT ? ks * (L_ / 64 / NSPL) : 0;   // 16 tiles per split
  const int ktEnd = SPLIT ? ktBeg + (L_ / 64 / NSPL) : (L_ / 64);
  const int lane = threadIdx.x & 63, wid = threadIdx.x >> 6;
  const int lq = lane & 31;          // q (QK) / d' (PV A) / col index
  const int hi = lane >> 5;          // lane-half: k-slice half selector
  const int q0 = qt * 128;
  const size_t tok0 = (size_t)b * L_;
  const ushort_t* qb = qk + tok0 * 2048 + h * HD_;
  const ushort_t* kb = qb + DIM_;
  const ushort_t* vb = vt + ((size_t)b * DIM_ + h * HD_) * L_;

  __shared__ ushort_t Ks[2][4096];   // [kpos 64][d 64], 16B-chunk XOR swizzle
  __shared__ ushort_t Vs[2][4096];   // [d 64][kpos 64], same swizzle

  const int srow0 = wid * 16 + (lane >> 3);
  const int sc    = (lane & 7) ^ (srow0 & 7);
  const ushort_t* kst = kb + (size_t)(ktBeg * 64 + srow0) * 2048 + sc * 8;
  const ushort_t* vst = vb + (size_t)srow0 * L_ + ktBeg * 64 + sc * 8;
  auto STAGE = [&](int bufi) {
    gload_lds16(kst,            &Ks[bufi][wid * 1024]);
    gload_lds16(kst + 8 * 2048, &Ks[bufi][wid * 1024 + 512]);
    gload_lds16(vst,            &Vs[bufi][wid * 1024]);
    gload_lds16(vst + 8 * L_,   &Vs[bufi][wid * 1024 + 512]);
    kst += 64 * 2048;
    vst += 64;
  };

  // Q fragments: B-operand of QK^T.  qf[s]: Q[q=lq][d = 16s + hi*8 + j]
  bf16x8 qf[4];
  {
    const ushort_t* gp = qb + (size_t)(q0 + wid * 32 + lq) * 2048;
#pragma unroll
    for (int s = 0; s < 4; ++s)
      qf[s] = *(const bf16x8*)(gp + s * 16 + hi * 8);
  }

  int chs[4];
#pragma unroll
  for (int s = 0; s < 4; ++s) chs[s] = ((2 * s + hi) ^ (lq & 7)) * 8;

  f32x16 oaccT[2] = {};              // [dtile] D[row=d'][col=q=lq]
  float mrow = 0.f;                  // absolute running max (shifted trigger)
  float lrow = 0.f;                  // per-lane half row-sum (cross-half at end)

  STAGE(0);
  __syncthreads();

  auto TILE = [&](int bi, bool more) {
    if (more) STAGE(bi ^ 1);
    const ushort_t* kb0 = &Ks[bi][lq * 64];
    const ushort_t* vb0 = &Vs[bi][lq * 64];

    // QK both half-tiles, C-init = -mrow: st = S - mrow (shifted domain)
    f32x16 st0, st1;
#pragma unroll
    for (int i = 0; i < 16; ++i) { st0[i] = -mrow; st1[i] = -mrow; }
    __builtin_amdgcn_s_setprio(1);
#pragma unroll
    for (int s = 0; s < 4; ++s) {
      bf16x8 kf0 = *(const bf16x8*)(kb0 + chs[s]);
      bf16x8 kf1 = *(const bf16x8*)(kb0 + 2048 + chs[s]);
      st0 = __builtin_amdgcn_mfma_f32_32x32x16_bf16(kf0, qf[s], st0, 0, 0, 0);
      st1 = __builtin_amdgcn_mfma_f32_32x32x16_bf16(kf1, qf[s], st1, 0, 0, 0);
    }
    __builtin_amdgcn_s_setprio(0);

    // joint shifted max over 32 values (max3 tree) + cross-half
    float a0 = fmax3(st0[0],  st0[1],  st0[2]);
    float a1 = fmax3(st0[3],  st0[4],  st0[5]);
    float a2 = fmax3(st0[6],  st0[7],  st0[8]);
    float a3 = fmax3(st0[9],  st0[10], st0[11]);
    float a4 = fmax3(st0[12], st0[13], st0[14]);
    float a5 = fmax3(st0[15], st1[0],  st1[1]);
    float a6 = fmax3(st1[2],  st1[3],  st1[4]);
    float a7 = fmax3(st1[5],  st1[6],  st1[7]);
    float a8 = fmax3(st1[8],  st1[9],  st1[10]);
    float a9 = fmax3(st1[11], st1[12], st1[13]);
    float aa = fmaxf(st1[14], st1[15]);
    float c0 = fmax3(a0, a1, a2);
    float c1 = fmax3(a3, a4, a5);
    float c2 = fmax3(a6, a7, a8);
    float c3 = fmax3(a9, aa, c0);
    float pm = fmax3(c1, c2, c3);
    pm = fmaxf(pm, __shfl_xor(pm, 32));

    // defer-max: rescale only when max grew by >8 over mrow (log2 domain)
    if (__any(pm > 8.f)) {
      float d = fmaxf(pm, 0.f);
      float alpha = __builtin_amdgcn_exp2f(-d);
      mrow += d;
      lrow *= alpha;
#pragma unroll
      for (int dt = 0; dt < 2; ++dt)
#pragma unroll
        for (int r = 0; r < 16; ++r) oaccT[dt][r] *= alpha;
#pragma unroll
      for (int i = 0; i < 16; ++i) { st0[i] -= d; st1[i] -= d; }
    }

    // P = exp2(st), packed bf16 pairs + VALU row-sum (4 partials for ILP)
    unsigned pk0[8], pk1[8];
    float rs0 = 0.f, rs1 = 0.f, rs2 = 0.f, rs3 = 0.f;
#pragma unroll
    for (int p = 0; p < 8; ++p) {
      float e0 = __builtin_amdgcn_exp2f(st0[2 * p]);
      float e1 = __builtin_amdgcn_exp2f(st0[2 * p + 1]);
      rs0 += e0; rs1 += e1;
      pk0[p] = (unsigned)f2b(e0) | ((unsigned)f2b(e1) << 16);
      float f0 = __builtin_amdgcn_exp2f(st1[2 * p]);
      float f1 = __builtin_amdgcn_exp2f(st1[2 * p + 1]);
      rs2 += f0; rs3 += f1;
      pk1[p] = (unsigned)f2b(f0) | ((unsigned)f2b(f1) << 16);
    }
    lrow += (rs0 + rs1) + (rs2 + rs3);

    // PV: redistribute P via permlane32_swap into B-fragments
    __builtin_amdgcn_s_setprio(1);
#pragma unroll
    for (int t = 0; t < 2; ++t)
#pragma unroll
      for (int blk = 0; blk < 2; ++blk) {
        unsigned w0 = (t == 0) ? pk0[4 * blk + 0] : pk1[4 * blk + 0];
        unsigned w1 = (t == 0) ? pk0[4 * blk + 1] : pk1[4 * blk + 1];
        unsigned w2 = (t == 0) ? pk0[4 * blk + 2] : pk1[4 * blk + 2];
        unsigned w3 = (t == 0) ? pk0[4 * blk + 3] : pk1[4 * blk + 3];
        plswap(w0, w2);   // -> {j0j1, j4j5}
        plswap(w1, w3);   // -> {j2j3, j6j7}
        uint4 bw; bw.x = w0; bw.y = w1; bw.z = w2; bw.w = w3;
        bf16x8 pf = __builtin_bit_cast(bf16x8, bw);
        const int sg = 2 * t + blk;
#pragma unroll
        for (int dt = 0; dt < 2; ++dt) {
          bf16x8 vf = *(const bf16x8*)(vb0 + dt * 2048 + chs[sg]);
          oaccT[dt] = __builtin_amdgcn_mfma_f32_32x32x16_bf16(vf, pf,
                                                              oaccT[dt], 0, 0, 0);
        }
      }
    __builtin_amdgcn_s_setprio(0);

    __syncthreads();   // drains vmcnt: stage(next) complete; buffers safe
  };

  const int NT = ktEnd - ktBeg;      // 16 (split) or 32 (single), even
  for (int it = 0; it < NT; it += 2) {
    TILE(0, it + 1 < NT);
    TILE(1, it + 2 < NT);
  }

  // epilogue: lane-local (q = lq); full row-sum needs cross-half add
  lrow += __shfl_xor(lrow, 32);
  const float linv = 1.f / lrow;
  const int tok = (int)tok0 + q0 + wid * 32 + lq;
  ushort_t* obp = (SPLIT ? Opart + (size_t)ks * M_ * DIM_ : O)
                  + (size_t)tok * DIM_ + h * HD_;
#pragma unroll
  for (int dt = 0; dt < 2; ++dt)
#pragma unroll
    for (int g4 = 0; g4 < 4; ++g4) {
      int d0 = dt * 32 + g4 * 8 + hi * 4;
      ushort4 o4;
      o4.x = f2b(oaccT[dt][4 * g4 + 0] * linv);
      o4.y = f2b(oaccT[dt][4 * g4 + 1] * linv);
      o4.z = f2b(oaccT[dt][4 * g4 + 2] * linv);
      o4.w = f2b(oaccT[dt][4 * g4 + 3] * linv);
      *(ushort4*)(obp + d0) = o4;
    }
  if (SPLIT && hi == 0) {
    float2 ml; ml.x = mrow; ml.y = lrow;
    *(float2*)&Ml[(((size_t)ks * M_ + tok) * H_ + h) * 2] = ml;
  }
}

// ---------------- combine NSPL K-split partials (bf16) -> bf16 O ----------------
// O = sum_i w_i*O_i, w_i = l_i*2^(m_i-M) / sum  (partials are normalized)
__global__ __launch_bounds__(256)
void attn_combine(const ushort_t* __restrict__ Opart, const float* __restrict__ Ml,
                  ushort_t* __restrict__ O) {
  int idx = blockIdx.x * 256 + threadIdx.x;   // 524288 threads, 8 bf16 each
  int c   = idx & 127;                        // chunk-of-8 within row
  int tok = idx >> 7;
  int h   = c >> 3;
  float2 ml[NSPL];
  float mM = -1e30f;
#pragma unroll
  for (int s = 0; s < NSPL; ++s) {
    ml[s] = *(const float2*)&Ml[(((size_t)s * M_ + tok) * H_ + h) * 2];
    mM = fmaxf(mM, ml[s].x);
  }
  float w[NSPL], sum = 0.f;
#pragma unroll
  for (int s = 0; s < NSPL; ++s) {
    w[s] = ml[s].y * __builtin_amdgcn_exp2f(ml[s].x - mM);
    sum += w[s];
  }
  float inv = 1.f / sum;
  size_t off = (size_t)tok * DIM_ + c * 8;
  float o[8] = {};
#pragma unroll
  for (int s = 0; s < NSPL; ++s) {
    uint4 a = *(const uint4*)&Opart[(size_t)s * M_ * DIM_ + off];
    float ws = w[s] * inv;
    const unsigned* pa = (const unsigned*)&a;
#pragma unroll
    for (int wd = 0; wd < 4; ++wd) {
      o[2 * wd]     += b2f((unsigned short)(pa[wd] & 0xffff)) * ws;
      o[2 * wd + 1] += b2f((unsigned short)(pa[wd] >> 16)) * ws;
    }
  }
  unsigned ow[4];
#pragma unroll
  for (int wd = 0; wd < 4; ++wd)
    ow[wd] = (unsigned)f2b(o[2 * wd]) | ((unsigned)f2b(o[2 * wd + 1]) << 16);
  uint4 ov; ov.x = ow[0]; ov.y = ow[1]; ov.z = ow[2]; ov.w = ow[3];
  *(uint4*)&O[off] = ov;
}

// ---------------- launch ----------------
extern "C" void kernel_launch(void* const* d_in, const int* in_sizes, int n_in,
                              void* d_out, int out_size, void* d_ws, size_t ws_size,
                              hipStream_t stream) {
  const float* x     = (const float*)d_in[0];
  const float* Wqkv  = (const float*)d_in[1];
  const float* qs    = (const float*)d_in[2];
  const float* ks    = (const float*)d_in[3];
  const float* Wproj = (const float*)d_in[4];
  const float* bproj = (const float*)d_in[5];
  float* out = (float*)d_out;

  char* ws = (char*)d_ws;
  ushort_t* xb     = (ushort_t*)(ws);                                  // 8 MB
  ushort_t* WqkvT  = (ushort_t*)(ws + (size_t)(8u << 20));             // 6 MB
  ushort_t* WprojT = (ushort_t*)(ws + (size_t)(14u << 20));            // 2 MB
  ushort_t* qkb    = (ushort_t*)(ws + (size_t)(16u << 20));            // 16 MB [4096][2048]
  ushort_t* vtb    = (ushort_t*)(ws + (size_t)(32u << 20));            // 8 MB  [2][1024][2048]
  float*    cosT   = (float*)(ws + (size_t)(40u << 20));               // 256 KB
  float*    sinT   = (float*)(ws + (size_t)(40u << 20) + (256u << 10));// 256 KB
  ushort_t* ob     = (ushort_t*)(ws + (size_t)(41u << 20));            // 8 MB
  ushort_t* Opart  = (ushort_t*)(ws + (size_t)(49u << 20));            // 16 MB [2][4096][1024] bf16
  float*    Ml     = (float*)(ws + (size_t)(65u << 20));               // 1 MB  [2][4096][16][2] f32

  preproc<<<5376, 256, 0, stream>>>(x, xb, Wqkv, WqkvT, Wproj, WprojT,
                                    cosT, sinT);
  gemm_qkv<<<dim3(24, 32), 256, 0, stream>>>(xb, WqkvT, qkb, vtb,
                                             qs, ks, cosT, sinT);
  if (ws_size >= ((size_t)66u << 20)) {
    flash_attn<1><<<dim3(16, 16, B_ * NSPL), 256, 0, stream>>>(qkb, vtb, nullptr,
                                                               Opart, Ml);
    attn_combine<<<2048, 256, 0, stream>>>(Opart, Ml, ob);
  } else {
    flash_attn<0><<<dim3(16, 16, 2), 256, 0, stream>>>(qkb, vtb, ob,
                                                       nullptr, nullptr);
  }
  gemm_proj<<<dim3(8, 32), 256, 0, stream>>>(ob, WprojT, out, bproj);
}